// Round 5
// baseline (280.007 us; speedup 1.0000x reference)
//
#include <hip/hip_runtime.h>

// B=4 T=4096 D=1024 H=16 HD=64 K=32 ; inputs f32, OUTPUTS f32.
// NO d_ws usage: all scratch lives inside the 67.1 MB f32 output-0 region.
// Zero atomics: split accumulations write disjoint per-z partial slabs,
// reduced by 2-stage trees (reduce_g then reduce_z/zp).
#define B_ 4
#define T_ 4096
#define D_ 1024
#define H_ 16
#define K_ 32

// ---------------------------------------------------------------------------
// Scratch layout (f32 indices into outF; out0 = floats [0, 16777216)):
//   xs    [0      ,131072)   B*K x 1024   [reduce_zp dst]
//   xbar  [131072 ,135168)   B x 1024     [reduce_zp dst, contiguous w/ xs]
//   pad   [135168 ,196608)   zeros (rows 132..191 of gemm#1 A) [reduce_zp]
//   qkv   [196608 ,786432)   192 x 3072   [reduce_z dst]
//   u     [786432 ,917504)   128 x 1024   [pure write, k3]
//   Mm    [917504 ,1048576)  128 x 1024   [reduce_z dst] = out0 rows [896,1024)
//   S     [1048576,...) partial slabs, sequentially reused:
//     k1 partials   : 64 z-records of 135168 = [1048576, 9699328)
//     k1 stage1     : 8 records of 135168    = [9699328, 10780672)   (S2)
//     gemm1 partials: 16 x 589824            = [1048576, 10485760)
//     gemm2 partials: 32 x 131072            = [1048576, 5242880)
//     gemm2 stage1  : 8 x 131072             = [5242880, 6291456)    (S3)
//   pulse outF[16777216 +64), resp outF[16777280 +2048)
// Each region is fully consumed before its successor overwrites it
// (in-order stream). k4_main overwrites rows [1024,16384) last.
// LDS broadcast rule (round-4 lesson): broadcast cost ~ RF delivery volume,
// NOT instruction count. Fix = raise FMA : broadcast-float ratio (here 4:1
// via 4 c/e per thread, k-halved blocks in k1).
// ---------------------------------------------------------------------------

__device__ __forceinline__ void fma4(float4& a, float s, const float4& v){
  a.x = fmaf(s, v.x, a.x); a.y = fmaf(s, v.y, a.y);
  a.z = fmaf(s, v.z, a.z); a.w = fmaf(s, v.w, a.w);
}

// reduce_g: dst[g*stride4+i] = sum_{zz<zper} src[(g*zper+zz)*stride4 + i]
// grid (ceil(n4/256), ngroups)
__global__ __launch_bounds__(256) void reduce_g(
    const float4* __restrict__ src, float4* __restrict__ dst,
    const int n4, const int zper, const int stride4)
{
  const int g = blockIdx.y;
  int i = blockIdx.x * 256 + threadIdx.x;
  if (i >= n4) return;
  float s0 = 0.f, s1 = 0.f, s2 = 0.f, s3 = 0.f;
  const float4* p = src + (size_t)g * zper * stride4 + i;
  #pragma unroll 4
  for (int zz = 0; zz < zper; ++zz){
    float4 v = p[(size_t)zz * stride4];
    s0 += v.x; s1 += v.y; s2 += v.z; s3 += v.w;
  }
  float4 o; o.x = s0; o.y = s1; o.z = s2; o.w = s3;
  dst[(size_t)g * stride4 + i] = o;
}

// reduce_zp: dst[i] = sum_z src[z*stride4+i] for i<n4; dst[i]=0 for
// n4<=i<total4 (zeroes gemm#1's pad rows).
__global__ __launch_bounds__(256) void reduce_zp(
    const float4* __restrict__ src, float4* __restrict__ dst,
    const int n4, const int z, const int stride4, const int total4)
{
  int i = blockIdx.x * 256 + threadIdx.x;
  if (i >= total4) return;
  if (i >= n4){
    float4 zv; zv.x = 0.f; zv.y = 0.f; zv.z = 0.f; zv.w = 0.f;
    dst[i] = zv; return;
  }
  float s0 = 0.f, s1 = 0.f, s2 = 0.f, s3 = 0.f;
  const float4* p = src + i;
  #pragma unroll 4
  for (int zz = 0; zz < z; ++zz){
    float4 v = p[(size_t)zz * stride4];
    s0 += v.x; s1 += v.y; s2 += v.z; s3 += v.w;
  }
  float4 o; o.x = s0; o.y = s1; o.z = s2; o.w = s3;
  dst[i] = o;
}

__global__ __launch_bounds__(256) void reduce_z(
    const float4* __restrict__ src, float4* __restrict__ dst,
    const int n4, const int z, const int stride4)
{
  int i = blockIdx.x * 256 + threadIdx.x;
  if (i >= n4) return;
  float s0 = 0.f, s1 = 0.f, s2 = 0.f, s3 = 0.f;
  const float4* p = src + i;
  #pragma unroll 4
  for (int zz = 0; zz < z; ++zz){
    float4 v = p[(size_t)zz * stride4];
    s0 += v.x; s1 += v.y; s2 += v.z; s3 += v.w;
  }
  float4 o; o.x = s0; o.y = s1; o.z = s2; o.w = s3;
  dst[i] = o;
}

// ---------------------------------------------------------------------------
// K1 (partials): XPz[b][k][c] = sum_{t in chunk z} sb[b,t,k]*x[b,t,c]
//                XPz[xbar][b][c] = sum_{t in chunk z} x[b,t,c]  (kh==0 only)
// grid (2, B, 64), block 256. blockIdx.x = k-half (16 k each).
// Thread owns 4 consecutive c (float4 x loads, 1KB/wave); covers full D.
// Per t: 16 broadcast floats vs 64 FMA -> 4:1 ratio (LDS return ~ VALU).
// z-record = 135168 floats: [ xs_z (131072) ; xbar_z (4096) ]; the two
// k-halves write disjoint k-rows of the same record.
// ---------------------------------------------------------------------------
__global__ __launch_bounds__(256) void k1_spectral_p(
    const float* __restrict__ x, const float* __restrict__ sb,
    float* __restrict__ XP)
{
  const int kh = blockIdx.x;
  const int b  = blockIdx.y;
  const int zz = blockIdx.z;
  const int t0 = zz * 64;
  const int c  = threadIdx.x * 4;
  __shared__ __align__(16) float sbs[64][20];   // 16 k + pad (80B rows)
  #pragma unroll
  for (int i = 0; i < 4; i++){
    int idx = threadIdx.x + i * 256;            // 1024 = 64t * 16k
    int t = idx >> 4, kk = idx & 15;
    sbs[t][kk] = sb[(size_t)(b * T_ + t0 + t) * K_ + kh * 16 + kk];
  }
  __syncthreads();
  float4 acc[16];
  #pragma unroll
  for (int k = 0; k < 16; k++){ acc[k].x = 0.f; acc[k].y = 0.f;
                                acc[k].z = 0.f; acc[k].w = 0.f; }
  float4 am; am.x = 0.f; am.y = 0.f; am.z = 0.f; am.w = 0.f;
  const float* xp = x + (size_t)(b * T_ + t0) * D_ + c;
  float4 p0 = *(const float4*)(xp);
  float4 p1 = *(const float4*)(xp + D_);
  float4 p2 = *(const float4*)(xp + 2 * D_);
  float4 p3 = *(const float4*)(xp + 3 * D_);
  #pragma unroll 4
  for (int t = 0; t < 64; ++t){
    float4 xv = p0; p0 = p1; p1 = p2; p2 = p3;
    if (t < 60) p3 = *(const float4*)(xp + (size_t)(t + 4) * D_);
    if (kh == 0){ am.x += xv.x; am.y += xv.y; am.z += xv.z; am.w += xv.w; }
    const float4* srow = (const float4*)&sbs[t][0];
    #pragma unroll
    for (int j = 0; j < 4; j++){
      float4 s4 = srow[j];
      fma4(acc[j * 4 + 0], s4.x, xv);
      fma4(acc[j * 4 + 1], s4.y, xv);
      fma4(acc[j * 4 + 2], s4.z, xv);
      fma4(acc[j * 4 + 3], s4.w, xv);
    }
  }
  float* o = XP + (size_t)zz * 135168 + (size_t)(b * K_ + kh * 16) * D_ + c;
  #pragma unroll
  for (int k = 0; k < 16; k++) *(float4*)(o + (size_t)k * D_) = acc[k];
  if (kh == 0)
    *(float4*)(XP + (size_t)zz * 135168 + 131072 + b * D_ + c) = am;
}

// ---------------------------------------------------------------------------
// gemm_aw_p: Cp[z][m][n] = sum_{c in split} A[m][c]*W[n][c]; PURE STORES.
// grid (N/64, M/64, csplit), block 256; 64x64 tile; c-chunk 32 (17.4 KB LDS).
// Register-staged double buffer.
// ---------------------------------------------------------------------------
__global__ __launch_bounds__(256) void gemm_aw_p(
    const float* __restrict__ A, const float* __restrict__ W,
    float* __restrict__ Cp, const int N, const int cPerSplit, const int MN)
{
  __shared__ __align__(16) float As[32][68];
  __shared__ __align__(16) float Ws[32][68];
  const int nt = blockIdx.x, mt = blockIdx.y;
  const int cbase = blockIdx.z * cPerSplit;
  const int tx = threadIdx.x & 15, ty = threadIdx.x >> 4;
  const int sc = threadIdx.x & 31, sr = threadIdx.x >> 5;  // staging coords
  float acc[4][4];
  #pragma unroll
  for (int i = 0; i < 4; i++)
    #pragma unroll
    for (int j = 0; j < 4; j++) acc[i][j] = 0.f;

  float ra[8], rw[8];
  const float* Ap = A + (size_t)(mt * 64 + sr) * 1024 + cbase + sc;
  const float* Wp = W + (size_t)(nt * 64 + sr) * 1024 + cbase + sc;
  #pragma unroll
  for (int i = 0; i < 8; i++){ ra[i] = Ap[(size_t)(i * 8) * 1024];
                               rw[i] = Wp[(size_t)(i * 8) * 1024]; }
  #pragma unroll
  for (int i = 0; i < 8; i++){ As[sc][sr + i * 8] = ra[i];
                               Ws[sc][sr + i * 8] = rw[i]; }
  __syncthreads();

  for (int cc = 32; cc < cPerSplit; cc += 32){
    #pragma unroll
    for (int i = 0; i < 8; i++){ ra[i] = Ap[(size_t)(i * 8) * 1024 + cc];
                                 rw[i] = Wp[(size_t)(i * 8) * 1024 + cc]; }
    #pragma unroll 4
    for (int c = 0; c < 32; ++c){
      const float4 a4 = *(const float4*)&As[c][ty * 4];
      const float4 w4 = *(const float4*)&Ws[c][tx * 4];
      acc[0][0] = fmaf(a4.x, w4.x, acc[0][0]);
      acc[0][1] = fmaf(a4.x, w4.y, acc[0][1]);
      acc[0][2] = fmaf(a4.x, w4.z, acc[0][2]);
      acc[0][3] = fmaf(a4.x, w4.w, acc[0][3]);
      acc[1][0] = fmaf(a4.y, w4.x, acc[1][0]);
      acc[1][1] = fmaf(a4.y, w4.y, acc[1][1]);
      acc[1][2] = fmaf(a4.y, w4.z, acc[1][2]);
      acc[1][3] = fmaf(a4.y, w4.w, acc[1][3]);
      acc[2][0] = fmaf(a4.z, w4.x, acc[2][0]);
      acc[2][1] = fmaf(a4.z, w4.y, acc[2][1]);
      acc[2][2] = fmaf(a4.z, w4.z, acc[2][2]);
      acc[2][3] = fmaf(a4.z, w4.w, acc[2][3]);
      acc[3][0] = fmaf(a4.w, w4.x, acc[3][0]);
      acc[3][1] = fmaf(a4.w, w4.y, acc[3][1]);
      acc[3][2] = fmaf(a4.w, w4.z, acc[3][2]);
      acc[3][3] = fmaf(a4.w, w4.w, acc[3][3]);
    }
    __syncthreads();
    #pragma unroll
    for (int i = 0; i < 8; i++){ As[sc][sr + i * 8] = ra[i];
                                 Ws[sc][sr + i * 8] = rw[i]; }
    __syncthreads();
  }
  #pragma unroll 4
  for (int c = 0; c < 32; ++c){
    const float4 a4 = *(const float4*)&As[c][ty * 4];
    const float4 w4 = *(const float4*)&Ws[c][tx * 4];
    acc[0][0] = fmaf(a4.x, w4.x, acc[0][0]);
    acc[0][1] = fmaf(a4.x, w4.y, acc[0][1]);
    acc[0][2] = fmaf(a4.x, w4.z, acc[0][2]);
    acc[0][3] = fmaf(a4.x, w4.w, acc[0][3]);
    acc[1][0] = fmaf(a4.y, w4.x, acc[1][0]);
    acc[1][1] = fmaf(a4.y, w4.y, acc[1][1]);
    acc[1][2] = fmaf(a4.y, w4.z, acc[1][2]);
    acc[1][3] = fmaf(a4.y, w4.w, acc[1][3]);
    acc[2][0] = fmaf(a4.z, w4.x, acc[2][0]);
    acc[2][1] = fmaf(a4.z, w4.y, acc[2][1]);
    acc[2][2] = fmaf(a4.z, w4.z, acc[2][2]);
    acc[2][3] = fmaf(a4.z, w4.w, acc[2][3]);
    acc[3][0] = fmaf(a4.w, w4.x, acc[3][0]);
    acc[3][1] = fmaf(a4.w, w4.y, acc[3][1]);
    acc[3][2] = fmaf(a4.w, w4.z, acc[3][2]);
    acc[3][3] = fmaf(a4.w, w4.w, acc[3][3]);
  }
  float* cp = Cp + (size_t)blockIdx.z * MN;
  #pragma unroll
  for (int i = 0; i < 4; i++){
    float4 o; o.x = acc[i][0]; o.y = acc[i][1]; o.z = acc[i][2]; o.w = acc[i][3];
    *(float4*)(cp + (size_t)(mt * 64 + ty * 4 + i) * N + nt * 64 + tx * 4) = o;
  }
}

// ---------------------------------------------------------------------------
// K3: pulse (qkv row 128+b = xbar@Wqkv.T), attn_spec, soliton ODE, u=resp*v_spec
// grid 64 blocks (b*16+h), 64 threads. All outputs f32.
// ---------------------------------------------------------------------------
__global__ __launch_bounds__(64) void k3_small(
    const float* __restrict__ qkvC,
    const float* __restrict__ W1, const float* __restrict__ b1,
    const float* __restrict__ W2, const float* __restrict__ b2,
    const float* __restrict__ filt,
    const float* __restrict__ a_in, const float* __restrict__ b_in,
    float* __restrict__ u, float* __restrict__ out_pulse,
    float* __restrict__ out_resp)
{
  const int b = blockIdx.x >> 4, h = blockIdx.x & 15;
  const int d = threadIdx.x;
  __shared__ float qm[64];
  __shared__ float h1s[32];
  __shared__ float rsp[32];
  qm[d] = qkvC[(size_t)(128 + b) * 3072 + h * 64 + d] * (1.0f / 4096.0f);
  __syncthreads();
  if (d < 32){
    float z = b1[d];
    for (int j = 0; j < 64; j++) z = fmaf(qm[j], W1[d * 64 + j], z);
    h1s[d] = z / (1.0f + __expf(-z));             // silu
  }
  __syncthreads();
  if (d == 0){
    float z2 = b2[0];
    for (int j = 0; j < 32; j++) z2 = fmaf(h1s[j], W2[j], z2);
    out_pulse[b * H_ + h] = 4.0f + log1pf(__expf(z2));  // PULSE_BASE+softplus
  }
  if (d < 32){
    const int k = d;
    const float* qrow = qkvC + (size_t)(b * K_ + k) * 3072 + h * 64;
    const float* krow = qrow + 1024;
    float s = 0.f;
    for (int j = 0; j < 64; j++) s = fmaf(qrow[j], krow[j], s);
    float fg = 1.0f / (1.0f + __expf(-filt[h * 32 + k]));
    s = s * 0.125f * fg;                          // /sqrt(64)*sigmoid(filter)
    float av = a_in[0], bv = b_in[0];
    float sc = fmaxf(fabsf(s), 1e-6f);
    float sn = s / sc;
    float I  = (fabsf(s) > 0.5f) ? sn : 0.1f * sn;
    float v = 0.f, w = 0.f;
    #pragma unroll
    for (int it = 0; it < 5; ++it){
      float dv = v - v * v * v * (1.0f / 3.0f) - w + I;
      float dw = (v + av - bv * w) * 10.0f;       // /TAU
      v = fminf(fmaxf(v + 0.2f * dv, -3.0f), 3.0f);
      w = fminf(fmaxf(w + 0.2f * dw, -3.0f), 3.0f);
    }
    float r = v * sc;
    rsp[k] = r;
    out_resp[(b * H_ + h) * K_ + k] = r;
  }
  __syncthreads();
  for (int k = 0; k < 32; k++){
    u[(size_t)(b * K_ + k) * D_ + h * 64 + d] =
        rsp[k] * qkvC[(size_t)(b * K_ + k) * 3072 + 2048 + h * 64 + d];
  }
}

// ---------------------------------------------------------------------------
// k4_main: all out0 rows EXCEPT [896,1024); 16-row chunks.
// grid (1016), block 256; thread owns 4 consecutive e (full D per block).
// M tile held in registers as float4[32]; float4 stores; 4:1 FMA:broadcast.
// ---------------------------------------------------------------------------
__global__ __launch_bounds__(256) void k4_main(
    const float* __restrict__ sb, const float* __restrict__ Mf,
    float* __restrict__ out)
{
  const int yy = blockIdx.x;
  const int r0 = (yy < 56 ? yy : yy + 8) * 16;   // skip M home rows [896,1024)
  const int b  = r0 >> 12;
  const int e0 = threadIdx.x * 4;
  __shared__ __align__(16) float sbs[16][36];
  #pragma unroll
  for (int i = 0; i < 2; i++){
    int idx = threadIdx.x + i * 256;           // 512 = 16t * 32k
    int k = idx & 31, t = idx >> 5;
    sbs[t][k] = sb[(size_t)(r0 + t) * K_ + k];
  }
  __syncthreads();
  float4 m4[32];
  const float* mp = Mf + (size_t)b * K_ * D_ + e0;
  #pragma unroll
  for (int k = 0; k < 32; k++) m4[k] = *(const float4*)(mp + (size_t)k * D_);
  float* op = out + (size_t)r0 * D_ + e0;
  #pragma unroll 4
  for (int t = 0; t < 16; ++t){
    float4 o4; o4.x = 0.f; o4.y = 0.f; o4.z = 0.f; o4.w = 0.f;
    const float4* srow = (const float4*)&sbs[t][0];
    #pragma unroll
    for (int j = 0; j < 8; j++){
      float4 s4 = srow[j];
      fma4(o4, s4.x, m4[j * 4 + 0]);
      fma4(o4, s4.y, m4[j * 4 + 1]);
      fma4(o4, s4.z, m4[j * 4 + 2]);
      fma4(o4, s4.w, m4[j * 4 + 3]);
    }
    *(float4*)(op + (size_t)t * D_) = o4;
  }
}

// ---------------------------------------------------------------------------
// k4_tailp: out0 rows [896,1024) — M's home — COLUMN-PARTITIONED.
// grid (64), block 256. Block j owns columns [j*16, j*16+16); race-free.
// ---------------------------------------------------------------------------
__global__ __launch_bounds__(256) void k4_tailp(
    const float* __restrict__ sb, const float* __restrict__ Mf,
    float* __restrict__ out)
{
  __shared__ float sbs[128][33];               // 16.9 KB
  __shared__ __align__(16) float Ms[32][16];   // 2 KB: this block's M columns
  const int j = blockIdx.x;
  #pragma unroll
  for (int i = 0; i < 2; i++){
    int idx = threadIdx.x + i * 256;           // 512 = 32k * 16e
    int k = idx >> 4, e = idx & 15;
    Ms[k][e] = Mf[(size_t)k * D_ + j * 16 + e];
  }
  #pragma unroll
  for (int i = 0; i < 16; i++){
    int idx = threadIdx.x + i * 256;           // 4096 = 128t * 32k
    int k = idx & 31, t = idx >> 5;
    sbs[t][k] = sb[(size_t)(896 + t) * K_ + k];
  }
  __syncthreads();
  const int t  = threadIdx.x >> 1;
  const int c0 = (threadIdx.x & 1) * 8;
  float a0 = 0.f, a1 = 0.f, a2 = 0.f, a3 = 0.f;
  float a4 = 0.f, a5 = 0.f, a6 = 0.f, a7 = 0.f;
  #pragma unroll
  for (int k = 0; k < 32; k++){
    float s = sbs[t][k];
    const float4 m0 = *(const float4*)&Ms[k][c0];
    const float4 m1 = *(const float4*)&Ms[k][c0 + 4];
    a0 = fmaf(s, m0.x, a0); a1 = fmaf(s, m0.y, a1);
    a2 = fmaf(s, m0.z, a2); a3 = fmaf(s, m0.w, a3);
    a4 = fmaf(s, m1.x, a4); a5 = fmaf(s, m1.y, a5);
    a6 = fmaf(s, m1.z, a6); a7 = fmaf(s, m1.w, a7);
  }
  float* op = out + (size_t)(896 + t) * D_ + j * 16 + c0;
  float4 o0; o0.x = a0; o0.y = a1; o0.z = a2; o0.w = a3;
  float4 o1; o1.x = a4; o1.y = a5; o1.z = a6; o1.w = a7;
  *(float4*)(op)     = o0;
  *(float4*)(op + 4) = o1;
}

// ---------------------------------------------------------------------------
extern "C" void kernel_launch(void* const* d_in, const int* in_sizes, int n_in,
                              void* d_out, int out_size, void* d_ws, size_t ws_size,
                              hipStream_t stream)
{
  const float* x    = (const float*)d_in[0];
  const float* sb   = (const float*)d_in[1];
  const float* Wqkv = (const float*)d_in[2];
  const float* Wout = (const float*)d_in[3];
  const float* a_in = (const float*)d_in[4];
  const float* b_in = (const float*)d_in[5];
  const float* W1   = (const float*)d_in[6];
  const float* b1   = (const float*)d_in[7];
  const float* W2   = (const float*)d_in[8];
  const float* b2   = (const float*)d_in[9];
  const float* filt = (const float*)d_in[10];

  float* outF = (float*)d_out;
  float* qkv  = outF + 196608;
  float* u    = outF + 786432;
  float* Mm   = outF + 917504;        // f32 M, out0 rows [896,1024)
  float* S    = outF + 1048576;       // partial slabs (sequentially reused)
  float* S2   = outF + 9699328;       // k1 reduce stage-1 (8 x 135168)
  float* S3   = outF + 5242880;       // gemm2 reduce stage-1 (8 x 131072)
  float* pulse = outF + 16777216;     // (B,H)   f32
  float* resp  = outF + 16777280;     // (B,H,K) f32

  // spectral projection partials (kh=2, b=4, z=64 t-chunks)
  k1_spectral_p<<<dim3(2, 4, 64), 256, 0, stream>>>(x, sb, S);
  // 2-stage reduce: 64 -> 8 -> 1 (+ zero gemm#1's pad rows)
  reduce_g<<<dim3(132, 8), 256, 0, stream>>>((const float4*)S, (float4*)S2,
                                             33792, 8, 33792);
  reduce_zp<<<dim3(192), 256, 0, stream>>>((const float4*)S2, (float4*)outF,
                                           33792, 8, 33792, 49152);

  // qkv GEMM: 16-way split-K partials -> reduce
  gemm_aw_p<<<dim3(48, 3, 16), 256, 0, stream>>>(outF, Wqkv, S, 3072, 64, 589824);
  reduce_z<<<dim3(576), 256, 0, stream>>>((const float4*)S, (float4*)qkv,
                                          147456, 16, 147456);

  k3_small<<<dim3(64), dim3(64), 0, stream>>>(qkv, W1, b1, W2, b2,
                                              filt, a_in, b_in, u,
                                              pulse, resp);

  // out GEMM: 32-way split-K partials -> 2-stage reduce: 32 -> 8 -> 1
  gemm_aw_p<<<dim3(16, 2, 32), 256, 0, stream>>>(u, Wout, S, 1024, 32, 131072);
  reduce_g<<<dim3(128, 8), 256, 0, stream>>>((const float4*)S, (float4*)S3,
                                             32768, 4, 32768);
  reduce_z<<<dim3(128), 256, 0, stream>>>((const float4*)S3, (float4*)Mm,
                                          32768, 8, 32768);

  // All rows except M's home, single launch, 16-row chunks, 4e/thread
  k4_main<<<dim3(1016), 256, 0, stream>>>(sb, Mm, outF);
  // M's home rows, column-partitioned across 64 blocks
  k4_tailp<<<dim3(64), 256, 0, stream>>>(sb, Mm, outF);
}

// Round 7
// 279.095 us; speedup vs baseline: 1.0033x; 1.0033x over previous
//
#include <hip/hip_runtime.h>

// B=4 T=4096 D=1024 H=16 HD=64 K=32 ; inputs f32, OUTPUTS f32.
// NO d_ws usage: all scratch lives inside the 67.1 MB f32 output-0 region.
// Zero atomics: split accumulations write disjoint per-z partial slabs,
// reduced by 2-stage trees (reduce_g then reduce_z/zp).
#define B_ 4
#define T_ 4096
#define D_ 1024
#define H_ 16
#define K_ 32

// ---------------------------------------------------------------------------
// Scratch layout (f32 indices into outF; out0 = floats [0, 16777216)):
//   xs    [0      ,131072)   B*K x 1024   [reduce_zp dst]
//   xbar  [131072 ,135168)   B x 1024     [reduce_zp dst, contiguous w/ xs]
//   pad   [135168 ,196608)   zeros (rows 132..191 of gemm#1 A) [reduce_zp]
//   qkv   [196608 ,786432)   192 x 3072   [reduce_z dst]
//   u     [786432 ,917504)   128 x 1024   [pure write, k3]
//   Mm    [917504 ,1048576)  128 x 1024   [reduce_z dst] = out0 rows [896,1024)
//   S     [1048576,...) partial slabs, sequentially reused:
//     k1 partials   : 64 z-records of 135168 = [1048576, 9699328)
//     k1 stage1     : 8 records of 135168    = [9699328, 10780672)   (S2)
//     gemm1 partials: 16 x 589824            = [1048576, 10485760)
//     gemm2 partials: 32 x 131072            = [1048576, 5242880)
//     gemm2 stage1  : 8 x 131072             = [5242880, 6291456)    (S3)
//   pulse outF[16777216 +64), resp outF[16777280 +2048)
// Each region is fully consumed before its successor overwrites it.
// k1 lesson (round 5): split D across blocks, NEVER K — K-splitting re-reads
// x from HBM (FETCH doubled) and shrinks the grid. Wave-uniform k-groups
// keep sbs reads pure broadcast; 4c/thread keeps FMA:broadcast at 4:1.
// ---------------------------------------------------------------------------

__device__ __forceinline__ void fma4(float4& a, float s, const float4& v){
  a.x = fmaf(s, v.x, a.x); a.y = fmaf(s, v.y, a.y);
  a.z = fmaf(s, v.z, a.z); a.w = fmaf(s, v.w, a.w);
}

// reduce_g: dst[g*stride4+i] = sum_{zz<zper} src[(g*zper+zz)*stride4 + i]
__global__ __launch_bounds__(256) void reduce_g(
    const float4* __restrict__ src, float4* __restrict__ dst,
    const int n4, const int zper, const int stride4)
{
  const int g = blockIdx.y;
  int i = blockIdx.x * 256 + threadIdx.x;
  if (i >= n4) return;
  float s0 = 0.f, s1 = 0.f, s2 = 0.f, s3 = 0.f;
  const float4* p = src + (size_t)g * zper * stride4 + i;
  #pragma unroll 4
  for (int zz = 0; zz < zper; ++zz){
    float4 v = p[(size_t)zz * stride4];
    s0 += v.x; s1 += v.y; s2 += v.z; s3 += v.w;
  }
  float4 o; o.x = s0; o.y = s1; o.z = s2; o.w = s3;
  dst[(size_t)g * stride4 + i] = o;
}

// reduce_zp: dst[i] = sum_z src[z*stride4+i] for i<n4; dst[i]=0 for
// n4<=i<total4 (zeroes gemm#1's pad rows).
__global__ __launch_bounds__(256) void reduce_zp(
    const float4* __restrict__ src, float4* __restrict__ dst,
    const int n4, const int z, const int stride4, const int total4)
{
  int i = blockIdx.x * 256 + threadIdx.x;
  if (i >= total4) return;
  if (i >= n4){
    float4 zv; zv.x = 0.f; zv.y = 0.f; zv.z = 0.f; zv.w = 0.f;
    dst[i] = zv; return;
  }
  float s0 = 0.f, s1 = 0.f, s2 = 0.f, s3 = 0.f;
  const float4* p = src + i;
  #pragma unroll 4
  for (int zz = 0; zz < z; ++zz){
    float4 v = p[(size_t)zz * stride4];
    s0 += v.x; s1 += v.y; s2 += v.z; s3 += v.w;
  }
  float4 o; o.x = s0; o.y = s1; o.z = s2; o.w = s3;
  dst[i] = o;
}

__global__ __launch_bounds__(256) void reduce_z(
    const float4* __restrict__ src, float4* __restrict__ dst,
    const int n4, const int z, const int stride4)
{
  int i = blockIdx.x * 256 + threadIdx.x;
  if (i >= n4) return;
  float s0 = 0.f, s1 = 0.f, s2 = 0.f, s3 = 0.f;
  const float4* p = src + i;
  #pragma unroll 4
  for (int zz = 0; zz < z; ++zz){
    float4 v = p[(size_t)zz * stride4];
    s0 += v.x; s1 += v.y; s2 += v.z; s3 += v.w;
  }
  float4 o; o.x = s0; o.y = s1; o.z = s2; o.w = s3;
  dst[i] = o;
}

// ---------------------------------------------------------------------------
// K1 (partials): XPz[b][k][c] = sum_{t in chunk z} sb[b,t,k]*x[b,t,c]
//                XPz[xbar][b][c] = sum_{t in chunk z} x[b,t,c]
// grid (4 c-tiles, B, 64 z), block 256. Full K=32 per block; x read ONCE.
// Wave kg = tid>>6 owns k's [kg*8, kg*8+8) -> sbs reads are wave-uniform
// broadcast (2KB/wave/t). cs = tid&63 owns 4 consecutive c (float4 loads,
// 1KB/wave). Per t: 1 float4 load + 8 broadcast floats + 32 FMA.
// acc = 32 VGPR -> ~70 total -> block-limited occupancy 16 waves/CU.
// z-record = 135168 floats: [ xs_z (131072) ; xbar_z (4096) ].
// ---------------------------------------------------------------------------
__global__ __launch_bounds__(256) void k1_spectral_p(
    const float* __restrict__ x, const float* __restrict__ sb,
    float* __restrict__ XP)
{
  const int ct = blockIdx.x;
  const int b  = blockIdx.y;
  const int zz = blockIdx.z;
  const int t0 = zz * 64;
  const int cs = threadIdx.x & 63;
  const int kg = threadIdx.x >> 6;          // == wave id
  const int c  = ct * 256 + cs * 4;
  __shared__ __align__(16) float sbs[64][36];
  #pragma unroll
  for (int i = 0; i < 8; i++){
    int idx = threadIdx.x + i * 256;        // 2048 = 64t * 32k
    int t = idx >> 5, kk = idx & 31;
    sbs[t][kk] = sb[(size_t)(b * T_ + t0 + t) * K_ + kk];
  }
  __syncthreads();
  float4 acc[8];
  #pragma unroll
  for (int k = 0; k < 8; k++){ acc[k].x = 0.f; acc[k].y = 0.f;
                               acc[k].z = 0.f; acc[k].w = 0.f; }
  float4 am; am.x = 0.f; am.y = 0.f; am.z = 0.f; am.w = 0.f;
  const float* xp = x + (size_t)(b * T_ + t0) * D_ + c;
  float4 p0 = *(const float4*)(xp);
  float4 p1 = *(const float4*)(xp + D_);
  float4 p2 = *(const float4*)(xp + 2 * D_);
  float4 p3 = *(const float4*)(xp + 3 * D_);
  #pragma unroll 4
  for (int t = 0; t < 64; ++t){
    float4 xv = p0; p0 = p1; p1 = p2; p2 = p3;
    if (t < 60) p3 = *(const float4*)(xp + (size_t)(t + 4) * D_);
    if (kg == 0){ am.x += xv.x; am.y += xv.y; am.z += xv.z; am.w += xv.w; }
    const float4* srow = (const float4*)&sbs[t][kg * 8];  // 16B aligned
    float4 s0 = srow[0], s1 = srow[1];
    fma4(acc[0], s0.x, xv); fma4(acc[1], s0.y, xv);
    fma4(acc[2], s0.z, xv); fma4(acc[3], s0.w, xv);
    fma4(acc[4], s1.x, xv); fma4(acc[5], s1.y, xv);
    fma4(acc[6], s1.z, xv); fma4(acc[7], s1.w, xv);
  }
  float* o = XP + (size_t)zz * 135168 + (size_t)(b * K_ + kg * 8) * D_ + c;
  #pragma unroll
  for (int k = 0; k < 8; k++) *(float4*)(o + (size_t)k * D_) = acc[k];
  if (kg == 0)
    *(float4*)(XP + (size_t)zz * 135168 + 131072 + b * D_ + c) = am;
}

// ---------------------------------------------------------------------------
// gemm_aw_p: Cp[z][m][n] = sum_{c in split} A[m][c]*W[n][c]; PURE STORES.
// grid (N/64, M/64, csplit), block 256; 64x64 tile; c-chunk 32 (17.4 KB LDS).
// Register-staged double buffer.
// ---------------------------------------------------------------------------
__global__ __launch_bounds__(256) void gemm_aw_p(
    const float* __restrict__ A, const float* __restrict__ W,
    float* __restrict__ Cp, const int N, const int cPerSplit, const int MN)
{
  __shared__ __align__(16) float As[32][68];
  __shared__ __align__(16) float Ws[32][68];
  const int nt = blockIdx.x, mt = blockIdx.y;
  const int cbase = blockIdx.z * cPerSplit;
  const int tx = threadIdx.x & 15, ty = threadIdx.x >> 4;
  const int sc = threadIdx.x & 31, sr = threadIdx.x >> 5;  // staging coords
  float acc[4][4];
  #pragma unroll
  for (int i = 0; i < 4; i++)
    #pragma unroll
    for (int j = 0; j < 4; j++) acc[i][j] = 0.f;

  float ra[8], rw[8];
  const float* Ap = A + (size_t)(mt * 64 + sr) * 1024 + cbase + sc;
  const float* Wp = W + (size_t)(nt * 64 + sr) * 1024 + cbase + sc;
  #pragma unroll
  for (int i = 0; i < 8; i++){ ra[i] = Ap[(size_t)(i * 8) * 1024];
                               rw[i] = Wp[(size_t)(i * 8) * 1024]; }
  #pragma unroll
  for (int i = 0; i < 8; i++){ As[sc][sr + i * 8] = ra[i];
                               Ws[sc][sr + i * 8] = rw[i]; }
  __syncthreads();

  for (int cc = 32; cc < cPerSplit; cc += 32){
    #pragma unroll
    for (int i = 0; i < 8; i++){ ra[i] = Ap[(size_t)(i * 8) * 1024 + cc];
                                 rw[i] = Wp[(size_t)(i * 8) * 1024 + cc]; }
    #pragma unroll 4
    for (int c = 0; c < 32; ++c){
      const float4 a4 = *(const float4*)&As[c][ty * 4];
      const float4 w4 = *(const float4*)&Ws[c][tx * 4];
      acc[0][0] = fmaf(a4.x, w4.x, acc[0][0]);
      acc[0][1] = fmaf(a4.x, w4.y, acc[0][1]);
      acc[0][2] = fmaf(a4.x, w4.z, acc[0][2]);
      acc[0][3] = fmaf(a4.x, w4.w, acc[0][3]);
      acc[1][0] = fmaf(a4.y, w4.x, acc[1][0]);
      acc[1][1] = fmaf(a4.y, w4.y, acc[1][1]);
      acc[1][2] = fmaf(a4.y, w4.z, acc[1][2]);
      acc[1][3] = fmaf(a4.y, w4.w, acc[1][3]);
      acc[2][0] = fmaf(a4.z, w4.x, acc[2][0]);
      acc[2][1] = fmaf(a4.z, w4.y, acc[2][1]);
      acc[2][2] = fmaf(a4.z, w4.z, acc[2][2]);
      acc[2][3] = fmaf(a4.z, w4.w, acc[2][3]);
      acc[3][0] = fmaf(a4.w, w4.x, acc[3][0]);
      acc[3][1] = fmaf(a4.w, w4.y, acc[3][1]);
      acc[3][2] = fmaf(a4.w, w4.z, acc[3][2]);
      acc[3][3] = fmaf(a4.w, w4.w, acc[3][3]);
    }
    __syncthreads();
    #pragma unroll
    for (int i = 0; i < 8; i++){ As[sc][sr + i * 8] = ra[i];
                                 Ws[sc][sr + i * 8] = rw[i]; }
    __syncthreads();
  }
  #pragma unroll 4
  for (int c = 0; c < 32; ++c){
    const float4 a4 = *(const float4*)&As[c][ty * 4];
    const float4 w4 = *(const float4*)&Ws[c][tx * 4];
    acc[0][0] = fmaf(a4.x, w4.x, acc[0][0]);
    acc[0][1] = fmaf(a4.x, w4.y, acc[0][1]);
    acc[0][2] = fmaf(a4.x, w4.z, acc[0][2]);
    acc[0][3] = fmaf(a4.x, w4.w, acc[0][3]);
    acc[1][0] = fmaf(a4.y, w4.x, acc[1][0]);
    acc[1][1] = fmaf(a4.y, w4.y, acc[1][1]);
    acc[1][2] = fmaf(a4.y, w4.z, acc[1][2]);
    acc[1][3] = fmaf(a4.y, w4.w, acc[1][3]);
    acc[2][0] = fmaf(a4.z, w4.x, acc[2][0]);
    acc[2][1] = fmaf(a4.z, w4.y, acc[2][1]);
    acc[2][2] = fmaf(a4.z, w4.z, acc[2][2]);
    acc[2][3] = fmaf(a4.z, w4.w, acc[2][3]);
    acc[3][0] = fmaf(a4.w, w4.x, acc[3][0]);
    acc[3][1] = fmaf(a4.w, w4.y, acc[3][1]);
    acc[3][2] = fmaf(a4.w, w4.z, acc[3][2]);
    acc[3][3] = fmaf(a4.w, w4.w, acc[3][3]);
  }
  float* cp = Cp + (size_t)blockIdx.z * MN;
  #pragma unroll
  for (int i = 0; i < 4; i++){
    float4 o; o.x = acc[i][0]; o.y = acc[i][1]; o.z = acc[i][2]; o.w = acc[i][3];
    *(float4*)(cp + (size_t)(mt * 64 + ty * 4 + i) * N + nt * 64 + tx * 4) = o;
  }
}

// ---------------------------------------------------------------------------
// K3: pulse (qkv row 128+b = xbar@Wqkv.T), attn_spec, soliton ODE, u=resp*v_spec
// grid 64 blocks (b*16+h), 64 threads. All outputs f32.
// ---------------------------------------------------------------------------
__global__ __launch_bounds__(64) void k3_small(
    const float* __restrict__ qkvC,
    const float* __restrict__ W1, const float* __restrict__ b1,
    const float* __restrict__ W2, const float* __restrict__ b2,
    const float* __restrict__ filt,
    const float* __restrict__ a_in, const float* __restrict__ b_in,
    float* __restrict__ u, float* __restrict__ out_pulse,
    float* __restrict__ out_resp)
{
  const int b = blockIdx.x >> 4, h = blockIdx.x & 15;
  const int d = threadIdx.x;
  __shared__ float qm[64];
  __shared__ float h1s[32];
  __shared__ float rsp[32];
  qm[d] = qkvC[(size_t)(128 + b) * 3072 + h * 64 + d] * (1.0f / 4096.0f);
  __syncthreads();
  if (d < 32){
    float z = b1[d];
    for (int j = 0; j < 64; j++) z = fmaf(qm[j], W1[d * 64 + j], z);
    h1s[d] = z / (1.0f + __expf(-z));             // silu
  }
  __syncthreads();
  if (d == 0){
    float z2 = b2[0];
    for (int j = 0; j < 32; j++) z2 = fmaf(h1s[j], W2[j], z2);
    out_pulse[b * H_ + h] = 4.0f + log1pf(__expf(z2));  // PULSE_BASE+softplus
  }
  if (d < 32){
    const int k = d;
    const float* qrow = qkvC + (size_t)(b * K_ + k) * 3072 + h * 64;
    const float* krow = qrow + 1024;
    float s = 0.f;
    for (int j = 0; j < 64; j++) s = fmaf(qrow[j], krow[j], s);
    float fg = 1.0f / (1.0f + __expf(-filt[h * 32 + k]));
    s = s * 0.125f * fg;                          // /sqrt(64)*sigmoid(filter)
    float av = a_in[0], bv = b_in[0];
    float sc = fmaxf(fabsf(s), 1e-6f);
    float sn = s / sc;
    float I  = (fabsf(s) > 0.5f) ? sn : 0.1f * sn;
    float v = 0.f, w = 0.f;
    #pragma unroll
    for (int it = 0; it < 5; ++it){
      float dv = v - v * v * v * (1.0f / 3.0f) - w + I;
      float dw = (v + av - bv * w) * 10.0f;       // /TAU
      v = fminf(fmaxf(v + 0.2f * dv, -3.0f), 3.0f);
      w = fminf(fmaxf(w + 0.2f * dw, -3.0f), 3.0f);
    }
    float r = v * sc;
    rsp[k] = r;
    out_resp[(b * H_ + h) * K_ + k] = r;
  }
  __syncthreads();
  for (int k = 0; k < 32; k++){
    u[(size_t)(b * K_ + k) * D_ + h * 64 + d] =
        rsp[k] * qkvC[(size_t)(b * K_ + k) * 3072 + 2048 + h * 64 + d];
  }
}

// ---------------------------------------------------------------------------
// k4_main: all out0 rows EXCEPT [896,1024); 16-row chunks.
// grid (1016), block 256; thread owns 4 consecutive e (full D per block).
// M tile held in registers as float4[32]; float4 stores.
// ---------------------------------------------------------------------------
__global__ __launch_bounds__(256) void k4_main(
    const float* __restrict__ sb, const float* __restrict__ Mf,
    float* __restrict__ out)
{
  const int yy = blockIdx.x;
  const int r0 = (yy < 56 ? yy : yy + 8) * 16;   // skip M home rows [896,1024)
  const int b  = r0 >> 12;
  const int e0 = threadIdx.x * 4;
  __shared__ __align__(16) float sbs[16][36];
  #pragma unroll
  for (int i = 0; i < 2; i++){
    int idx = threadIdx.x + i * 256;           // 512 = 16t * 32k
    int k = idx & 31, t = idx >> 5;
    sbs[t][k] = sb[(size_t)(r0 + t) * K_ + k];
  }
  __syncthreads();
  float4 m4[32];
  const float* mp = Mf + (size_t)b * K_ * D_ + e0;
  #pragma unroll
  for (int k = 0; k < 32; k++) m4[k] = *(const float4*)(mp + (size_t)k * D_);
  float* op = out + (size_t)r0 * D_ + e0;
  #pragma unroll 4
  for (int t = 0; t < 16; ++t){
    float4 o4; o4.x = 0.f; o4.y = 0.f; o4.z = 0.f; o4.w = 0.f;
    const float4* srow = (const float4*)&sbs[t][0];
    #pragma unroll
    for (int j = 0; j < 8; j++){
      float4 s4 = srow[j];
      fma4(o4, s4.x, m4[j * 4 + 0]);
      fma4(o4, s4.y, m4[j * 4 + 1]);
      fma4(o4, s4.z, m4[j * 4 + 2]);
      fma4(o4, s4.w, m4[j * 4 + 3]);
    }
    *(float4*)(op + (size_t)t * D_) = o4;
  }
}

// ---------------------------------------------------------------------------
// k4_tailp: out0 rows [896,1024) — M's home — COLUMN-PARTITIONED.
// grid (64), block 256. Block j owns columns [j*16, j*16+16); race-free.
// ---------------------------------------------------------------------------
__global__ __launch_bounds__(256) void k4_tailp(
    const float* __restrict__ sb, const float* __restrict__ Mf,
    float* __restrict__ out)
{
  __shared__ float sbs[128][33];               // 16.9 KB
  __shared__ __align__(16) float Ms[32][16];   // 2 KB: this block's M columns
  const int j = blockIdx.x;
  #pragma unroll
  for (int i = 0; i < 2; i++){
    int idx = threadIdx.x + i * 256;           // 512 = 32k * 16e
    int k = idx >> 4, e = idx & 15;
    Ms[k][e] = Mf[(size_t)k * D_ + j * 16 + e];
  }
  #pragma unroll
  for (int i = 0; i < 16; i++){
    int idx = threadIdx.x + i * 256;           // 4096 = 128t * 32k
    int k = idx & 31, t = idx >> 5;
    sbs[t][k] = sb[(size_t)(896 + t) * K_ + k];
  }
  __syncthreads();
  const int t  = threadIdx.x >> 1;
  const int c0 = (threadIdx.x & 1) * 8;
  float a0 = 0.f, a1 = 0.f, a2 = 0.f, a3 = 0.f;
  float a4 = 0.f, a5 = 0.f, a6 = 0.f, a7 = 0.f;
  #pragma unroll
  for (int k = 0; k < 32; k++){
    float s = sbs[t][k];
    const float4 m0 = *(const float4*)&Ms[k][c0];
    const float4 m1 = *(const float4*)&Ms[k][c0 + 4];
    a0 = fmaf(s, m0.x, a0); a1 = fmaf(s, m0.y, a1);
    a2 = fmaf(s, m0.z, a2); a3 = fmaf(s, m0.w, a3);
    a4 = fmaf(s, m1.x, a4); a5 = fmaf(s, m1.y, a5);
    a6 = fmaf(s, m1.z, a6); a7 = fmaf(s, m1.w, a7);
  }
  float* op = out + (size_t)(896 + t) * D_ + j * 16 + c0;
  float4 o0; o0.x = a0; o0.y = a1; o0.z = a2; o0.w = a3;
  float4 o1; o1.x = a4; o1.y = a5; o1.z = a6; o1.w = a7;
  *(float4*)(op)     = o0;
  *(float4*)(op + 4) = o1;
}

// ---------------------------------------------------------------------------
extern "C" void kernel_launch(void* const* d_in, const int* in_sizes, int n_in,
                              void* d_out, int out_size, void* d_ws, size_t ws_size,
                              hipStream_t stream)
{
  const float* x    = (const float*)d_in[0];
  const float* sb   = (const float*)d_in[1];
  const float* Wqkv = (const float*)d_in[2];
  const float* Wout = (const float*)d_in[3];
  const float* a_in = (const float*)d_in[4];
  const float* b_in = (const float*)d_in[5];
  const float* W1   = (const float*)d_in[6];
  const float* b1   = (const float*)d_in[7];
  const float* W2   = (const float*)d_in[8];
  const float* b2   = (const float*)d_in[9];
  const float* filt = (const float*)d_in[10];

  float* outF = (float*)d_out;
  float* qkv  = outF + 196608;
  float* u    = outF + 786432;
  float* Mm   = outF + 917504;        // f32 M, out0 rows [896,1024)
  float* S    = outF + 1048576;       // partial slabs (sequentially reused)
  float* S2   = outF + 9699328;       // k1 reduce stage-1 (8 x 135168)
  float* S3   = outF + 5242880;       // gemm2 reduce stage-1 (8 x 131072)
  float* pulse = outF + 16777216;     // (B,H)   f32
  float* resp  = outF + 16777280;     // (B,H,K) f32

  // spectral projection partials (4 c-tiles, b=4, z=64 t-chunks); x read once
  k1_spectral_p<<<dim3(4, 4, 64), 256, 0, stream>>>(x, sb, S);
  // 2-stage reduce: 64 -> 8 -> 1 (+ zero gemm#1's pad rows)
  reduce_g<<<dim3(132, 8), 256, 0, stream>>>((const float4*)S, (float4*)S2,
                                             33792, 8, 33792);
  reduce_zp<<<dim3(192), 256, 0, stream>>>((const float4*)S2, (float4*)outF,
                                           33792, 8, 33792, 49152);

  // qkv GEMM: 16-way split-K partials -> reduce
  gemm_aw_p<<<dim3(48, 3, 16), 256, 0, stream>>>(outF, Wqkv, S, 3072, 64, 589824);
  reduce_z<<<dim3(576), 256, 0, stream>>>((const float4*)S, (float4*)qkv,
                                          147456, 16, 147456);

  k3_small<<<dim3(64), dim3(64), 0, stream>>>(qkv, W1, b1, W2, b2,
                                              filt, a_in, b_in, u,
                                              pulse, resp);

  // out GEMM: 32-way split-K partials -> 2-stage reduce: 32 -> 8 -> 1
  gemm_aw_p<<<dim3(16, 2, 32), 256, 0, stream>>>(u, Wout, S, 1024, 32, 131072);
  reduce_g<<<dim3(128, 8), 256, 0, stream>>>((const float4*)S, (float4*)S3,
                                             32768, 4, 32768);
  reduce_z<<<dim3(128), 256, 0, stream>>>((const float4*)S3, (float4*)Mm,
                                          32768, 8, 32768);

  // All rows except M's home, single launch, 16-row chunks, 4e/thread
  k4_main<<<dim3(1016), 256, 0, stream>>>(sb, Mm, outF);
  // M's home rows, column-partitioned across 64 blocks
  k4_tailp<<<dim3(64), 256, 0, stream>>>(sb, Mm, outF);
}

// Round 8
// 261.191 us; speedup vs baseline: 1.0720x; 1.0685x over previous
//
#include <hip/hip_runtime.h>

// B=4 T=4096 D=1024 H=16 HD=64 K=32 ; inputs f32, OUTPUTS f32.
// NO d_ws usage: all scratch lives inside the 67.1 MB f32 output-0 region.
// Zero atomics: split accumulations write disjoint per-z partial slabs,
// reduced by 2-stage trees (reduce_g then reduce_z/zp).
#define B_ 4
#define T_ 4096
#define D_ 1024
#define H_ 16
#define K_ 32

// ---------------------------------------------------------------------------
// Scratch layout (f32 indices into outF; out0 = floats [0, 16777216)):
//   xs    [0      ,131072)   B*K x 1024   [reduce_zp dst]
//   xbar  [131072 ,135168)   B x 1024     [reduce_zp dst, contiguous w/ xs]
//   pad   [135168 ,196608)   zeros (rows 132..191 of gemm#1 A) [reduce_zp]
//   qkv   [196608 ,786432)   192 x 3072   [reduce_z dst]
//   u     [786432 ,917504)   128 x 1024   [pure write, k3]
//   Mm    [917504 ,1048576)  128 x 1024   [reduce_z dst] = out0 rows [896,1024)
//   S     [1048576,...) partial slabs, sequentially reused:
//     k1 partials   : 64 z-records of 135168 = [1048576, 9699328)
//     k1 stage1     : 8 records of 135168    = [9699328, 10780672)   (S2)
//     gemm1 partials: 16 x 589824            = [1048576, 10485760)
//     gemm2 partials: 32 x 131072            = [1048576, 5242880)
//     gemm2 stage1  : 8 x 131072             = [5242880, 6291456)    (S3)
//   pulse outF[16777216 +64), resp outF[16777280 +2048)
// Each region is fully consumed before its successor overwrites it.
// k1 lesson (round 7): the bound was never BW/VALU/LDS — it was the per-wave
// DEPENDENT load stream (rotating prefetch ~ depth<=4, ~2000cy effective per
// iter). Fix: memcpy-shaped staging — burst 16 independent float4 loads into
// LDS, no use-dependency until the barrier; compute reads x from LDS.
// ---------------------------------------------------------------------------

__device__ __forceinline__ void fma4(float4& a, float s, const float4& v){
  a.x = fmaf(s, v.x, a.x); a.y = fmaf(s, v.y, a.y);
  a.z = fmaf(s, v.z, a.z); a.w = fmaf(s, v.w, a.w);
}

// reduce_g: dst[g*stride4+i] = sum_{zz<zper} src[(g*zper+zz)*stride4 + i]
__global__ __launch_bounds__(256) void reduce_g(
    const float4* __restrict__ src, float4* __restrict__ dst,
    const int n4, const int zper, const int stride4)
{
  const int g = blockIdx.y;
  int i = blockIdx.x * 256 + threadIdx.x;
  if (i >= n4) return;
  float s0 = 0.f, s1 = 0.f, s2 = 0.f, s3 = 0.f;
  const float4* p = src + (size_t)g * zper * stride4 + i;
  #pragma unroll 8
  for (int zz = 0; zz < zper; ++zz){
    float4 v = p[(size_t)zz * stride4];
    s0 += v.x; s1 += v.y; s2 += v.z; s3 += v.w;
  }
  float4 o; o.x = s0; o.y = s1; o.z = s2; o.w = s3;
  dst[(size_t)g * stride4 + i] = o;
}

// reduce_zp: dst[i] = sum_z src[z*stride4+i] for i<n4; dst[i]=0 for
// n4<=i<total4 (zeroes gemm#1's pad rows).
__global__ __launch_bounds__(256) void reduce_zp(
    const float4* __restrict__ src, float4* __restrict__ dst,
    const int n4, const int z, const int stride4, const int total4)
{
  int i = blockIdx.x * 256 + threadIdx.x;
  if (i >= total4) return;
  if (i >= n4){
    float4 zv; zv.x = 0.f; zv.y = 0.f; zv.z = 0.f; zv.w = 0.f;
    dst[i] = zv; return;
  }
  float s0 = 0.f, s1 = 0.f, s2 = 0.f, s3 = 0.f;
  const float4* p = src + i;
  #pragma unroll 8
  for (int zz = 0; zz < z; ++zz){
    float4 v = p[(size_t)zz * stride4];
    s0 += v.x; s1 += v.y; s2 += v.z; s3 += v.w;
  }
  float4 o; o.x = s0; o.y = s1; o.z = s2; o.w = s3;
  dst[i] = o;
}

__global__ __launch_bounds__(256) void reduce_z(
    const float4* __restrict__ src, float4* __restrict__ dst,
    const int n4, const int z, const int stride4)
{
  int i = blockIdx.x * 256 + threadIdx.x;
  if (i >= n4) return;
  float s0 = 0.f, s1 = 0.f, s2 = 0.f, s3 = 0.f;
  const float4* p = src + i;
  #pragma unroll 8
  for (int zz = 0; zz < z; ++zz){
    float4 v = p[(size_t)zz * stride4];
    s0 += v.x; s1 += v.y; s2 += v.z; s3 += v.w;
  }
  float4 o; o.x = s0; o.y = s1; o.z = s2; o.w = s3;
  dst[i] = o;
}

// ---------------------------------------------------------------------------
// K1 (partials): XPz[b][k][c] = sum_{t in chunk z} sb[b,t,k]*x[b,t,c]
//                XPz[xbar][b][c] = sum_{t in chunk z} x[b,t,c]
// grid (4 c-tiles, B, 64 z), block 256. Full K=32 per block; x read ONCE.
// STAGE: 16 independent float4 loads/thread (memcpy-shaped, depth 16) into
// a 64t x 256c LDS tile, + sb tile; one barrier; COMPUTE: per t, x from LDS
// (b128 conflict-free) + 2 wave-uniform sbs broadcasts + 32 FMA.
// LDS = 65536 + 9216 = 74752 B -> 2 blocks/CU; one block's staging burst
// overlaps the other's compute (TLP covers the phase boundary).
// z-record = 135168 floats: [ xs_z (131072) ; xbar_z (4096) ].
// ---------------------------------------------------------------------------
__global__ __launch_bounds__(256) void k1_spectral_p(
    const float* __restrict__ x, const float* __restrict__ sb,
    float* __restrict__ XP)
{
  const int ct = blockIdx.x;
  const int b  = blockIdx.y;
  const int zz = blockIdx.z;
  const int t0 = zz * 64;
  const int cs = threadIdx.x & 63;
  const int kg = threadIdx.x >> 6;          // == wave id
  __shared__ __align__(16) float4 xt[4096];   // 64t x 64 float4 (256 c) 64KB
  __shared__ __align__(16) float sbs[64][36]; // 9.2KB
  // stage sb (2048 elems)
  #pragma unroll
  for (int i = 0; i < 8; i++){
    int idx = threadIdx.x + i * 256;        // 2048 = 64t * 32k
    int t = idx >> 5, kk = idx & 31;
    sbs[t][kk] = sb[(size_t)(b * T_ + t0 + t) * K_ + kk];
  }
  // stage x tile: 16 independent loads (no use-dep), then 16 ds_writes
  const float4* xg = (const float4*)(x + (size_t)(b * T_ + t0) * D_ + ct * 256);
  float4 rv[16];
  #pragma unroll
  for (int j = 0; j < 16; j++){
    int idx = threadIdx.x + j * 256;        // 4096 float4 = 64t * 64cq
    int t = idx >> 6, cq = idx & 63;
    rv[j] = xg[(size_t)t * 256 + cq];       // global row stride 256 float4
  }
  #pragma unroll
  for (int j = 0; j < 16; j++) xt[threadIdx.x + j * 256] = rv[j];
  __syncthreads();

  float4 acc[8];
  #pragma unroll
  for (int k = 0; k < 8; k++){ acc[k].x = 0.f; acc[k].y = 0.f;
                               acc[k].z = 0.f; acc[k].w = 0.f; }
  float4 am; am.x = 0.f; am.y = 0.f; am.z = 0.f; am.w = 0.f;
  #pragma unroll 4
  for (int t = 0; t < 64; ++t){
    float4 xv = xt[t * 64 + cs];            // b128, lanes contiguous
    if (kg == 0){ am.x += xv.x; am.y += xv.y; am.z += xv.z; am.w += xv.w; }
    const float4* srow = (const float4*)&sbs[t][kg * 8];  // wave-uniform
    float4 s0 = srow[0], s1 = srow[1];
    fma4(acc[0], s0.x, xv); fma4(acc[1], s0.y, xv);
    fma4(acc[2], s0.z, xv); fma4(acc[3], s0.w, xv);
    fma4(acc[4], s1.x, xv); fma4(acc[5], s1.y, xv);
    fma4(acc[6], s1.z, xv); fma4(acc[7], s1.w, xv);
  }
  const int c = ct * 256 + cs * 4;
  float* o = XP + (size_t)zz * 135168 + (size_t)(b * K_ + kg * 8) * D_ + c;
  #pragma unroll
  for (int k = 0; k < 8; k++) *(float4*)(o + (size_t)k * D_) = acc[k];
  if (kg == 0)
    *(float4*)(XP + (size_t)zz * 135168 + 131072 + b * D_ + c) = am;
}

// ---------------------------------------------------------------------------
// gemm_aw_p: Cp[z][m][n] = sum_{c in split} A[m][c]*W[n][c]; PURE STORES.
// grid (N/64, M/64, csplit), block 256; 64x64 tile; c-chunk 32 (17.4 KB LDS).
// Register-staged double buffer.
// ---------------------------------------------------------------------------
__global__ __launch_bounds__(256) void gemm_aw_p(
    const float* __restrict__ A, const float* __restrict__ W,
    float* __restrict__ Cp, const int N, const int cPerSplit, const int MN)
{
  __shared__ __align__(16) float As[32][68];
  __shared__ __align__(16) float Ws[32][68];
  const int nt = blockIdx.x, mt = blockIdx.y;
  const int cbase = blockIdx.z * cPerSplit;
  const int tx = threadIdx.x & 15, ty = threadIdx.x >> 4;
  const int sc = threadIdx.x & 31, sr = threadIdx.x >> 5;  // staging coords
  float acc[4][4];
  #pragma unroll
  for (int i = 0; i < 4; i++)
    #pragma unroll
    for (int j = 0; j < 4; j++) acc[i][j] = 0.f;

  float ra[8], rw[8];
  const float* Ap = A + (size_t)(mt * 64 + sr) * 1024 + cbase + sc;
  const float* Wp = W + (size_t)(nt * 64 + sr) * 1024 + cbase + sc;
  #pragma unroll
  for (int i = 0; i < 8; i++){ ra[i] = Ap[(size_t)(i * 8) * 1024];
                               rw[i] = Wp[(size_t)(i * 8) * 1024]; }
  #pragma unroll
  for (int i = 0; i < 8; i++){ As[sc][sr + i * 8] = ra[i];
                               Ws[sc][sr + i * 8] = rw[i]; }
  __syncthreads();

  for (int cc = 32; cc < cPerSplit; cc += 32){
    #pragma unroll
    for (int i = 0; i < 8; i++){ ra[i] = Ap[(size_t)(i * 8) * 1024 + cc];
                                 rw[i] = Wp[(size_t)(i * 8) * 1024 + cc]; }
    #pragma unroll 4
    for (int c = 0; c < 32; ++c){
      const float4 a4 = *(const float4*)&As[c][ty * 4];
      const float4 w4 = *(const float4*)&Ws[c][tx * 4];
      acc[0][0] = fmaf(a4.x, w4.x, acc[0][0]);
      acc[0][1] = fmaf(a4.x, w4.y, acc[0][1]);
      acc[0][2] = fmaf(a4.x, w4.z, acc[0][2]);
      acc[0][3] = fmaf(a4.x, w4.w, acc[0][3]);
      acc[1][0] = fmaf(a4.y, w4.x, acc[1][0]);
      acc[1][1] = fmaf(a4.y, w4.y, acc[1][1]);
      acc[1][2] = fmaf(a4.y, w4.z, acc[1][2]);
      acc[1][3] = fmaf(a4.y, w4.w, acc[1][3]);
      acc[2][0] = fmaf(a4.z, w4.x, acc[2][0]);
      acc[2][1] = fmaf(a4.z, w4.y, acc[2][1]);
      acc[2][2] = fmaf(a4.z, w4.z, acc[2][2]);
      acc[2][3] = fmaf(a4.z, w4.w, acc[2][3]);
      acc[3][0] = fmaf(a4.w, w4.x, acc[3][0]);
      acc[3][1] = fmaf(a4.w, w4.y, acc[3][1]);
      acc[3][2] = fmaf(a4.w, w4.z, acc[3][2]);
      acc[3][3] = fmaf(a4.w, w4.w, acc[3][3]);
    }
    __syncthreads();
    #pragma unroll
    for (int i = 0; i < 8; i++){ As[sc][sr + i * 8] = ra[i];
                                 Ws[sc][sr + i * 8] = rw[i]; }
    __syncthreads();
  }
  #pragma unroll 4
  for (int c = 0; c < 32; ++c){
    const float4 a4 = *(const float4*)&As[c][ty * 4];
    const float4 w4 = *(const float4*)&Ws[c][tx * 4];
    acc[0][0] = fmaf(a4.x, w4.x, acc[0][0]);
    acc[0][1] = fmaf(a4.x, w4.y, acc[0][1]);
    acc[0][2] = fmaf(a4.x, w4.z, acc[0][2]);
    acc[0][3] = fmaf(a4.x, w4.w, acc[0][3]);
    acc[1][0] = fmaf(a4.y, w4.x, acc[1][0]);
    acc[1][1] = fmaf(a4.y, w4.y, acc[1][1]);
    acc[1][2] = fmaf(a4.y, w4.z, acc[1][2]);
    acc[1][3] = fmaf(a4.y, w4.w, acc[1][3]);
    acc[2][0] = fmaf(a4.z, w4.x, acc[2][0]);
    acc[2][1] = fmaf(a4.z, w4.y, acc[2][1]);
    acc[2][2] = fmaf(a4.z, w4.z, acc[2][2]);
    acc[2][3] = fmaf(a4.z, w4.w, acc[2][3]);
    acc[3][0] = fmaf(a4.w, w4.x, acc[3][0]);
    acc[3][1] = fmaf(a4.w, w4.y, acc[3][1]);
    acc[3][2] = fmaf(a4.w, w4.z, acc[3][2]);
    acc[3][3] = fmaf(a4.w, w4.w, acc[3][3]);
  }
  float* cp = Cp + (size_t)blockIdx.z * MN;
  #pragma unroll
  for (int i = 0; i < 4; i++){
    float4 o; o.x = acc[i][0]; o.y = acc[i][1]; o.z = acc[i][2]; o.w = acc[i][3];
    *(float4*)(cp + (size_t)(mt * 64 + ty * 4 + i) * N + nt * 64 + tx * 4) = o;
  }
}

// ---------------------------------------------------------------------------
// K3: pulse (qkv row 128+b = xbar@Wqkv.T), attn_spec, soliton ODE, u=resp*v_spec
// grid 64 blocks (b*16+h), 64 threads. All outputs f32.
// ---------------------------------------------------------------------------
__global__ __launch_bounds__(64) void k3_small(
    const float* __restrict__ qkvC,
    const float* __restrict__ W1, const float* __restrict__ b1,
    const float* __restrict__ W2, const float* __restrict__ b2,
    const float* __restrict__ filt,
    const float* __restrict__ a_in, const float* __restrict__ b_in,
    float* __restrict__ u, float* __restrict__ out_pulse,
    float* __restrict__ out_resp)
{
  const int b = blockIdx.x >> 4, h = blockIdx.x & 15;
  const int d = threadIdx.x;
  __shared__ float qm[64];
  __shared__ float h1s[32];
  __shared__ float rsp[32];
  qm[d] = qkvC[(size_t)(128 + b) * 3072 + h * 64 + d] * (1.0f / 4096.0f);
  __syncthreads();
  if (d < 32){
    float z = b1[d];
    for (int j = 0; j < 64; j++) z = fmaf(qm[j], W1[d * 64 + j], z);
    h1s[d] = z / (1.0f + __expf(-z));             // silu
  }
  __syncthreads();
  if (d == 0){
    float z2 = b2[0];
    for (int j = 0; j < 32; j++) z2 = fmaf(h1s[j], W2[j], z2);
    out_pulse[b * H_ + h] = 4.0f + log1pf(__expf(z2));  // PULSE_BASE+softplus
  }
  if (d < 32){
    const int k = d;
    const float* qrow = qkvC + (size_t)(b * K_ + k) * 3072 + h * 64;
    const float* krow = qrow + 1024;
    float s = 0.f;
    for (int j = 0; j < 64; j++) s = fmaf(qrow[j], krow[j], s);
    float fg = 1.0f / (1.0f + __expf(-filt[h * 32 + k]));
    s = s * 0.125f * fg;                          // /sqrt(64)*sigmoid(filter)
    float av = a_in[0], bv = b_in[0];
    float sc = fmaxf(fabsf(s), 1e-6f);
    float sn = s / sc;
    float I  = (fabsf(s) > 0.5f) ? sn : 0.1f * sn;
    float v = 0.f, w = 0.f;
    #pragma unroll
    for (int it = 0; it < 5; ++it){
      float dv = v - v * v * v * (1.0f / 3.0f) - w + I;
      float dw = (v + av - bv * w) * 10.0f;       // /TAU
      v = fminf(fmaxf(v + 0.2f * dv, -3.0f), 3.0f);
      w = fminf(fmaxf(w + 0.2f * dw, -3.0f), 3.0f);
    }
    float r = v * sc;
    rsp[k] = r;
    out_resp[(b * H_ + h) * K_ + k] = r;
  }
  __syncthreads();
  for (int k = 0; k < 32; k++){
    u[(size_t)(b * K_ + k) * D_ + h * 64 + d] =
        rsp[k] * qkvC[(size_t)(b * K_ + k) * 3072 + 2048 + h * 64 + d];
  }
}

// ---------------------------------------------------------------------------
// k4_main: all out0 rows EXCEPT [896,1024); 16-row chunks.
// grid (1016), block 256; thread owns 4 consecutive e (full D per block).
// M tile held in registers as float4[32]; float4 stores.
// ---------------------------------------------------------------------------
__global__ __launch_bounds__(256) void k4_main(
    const float* __restrict__ sb, const float* __restrict__ Mf,
    float* __restrict__ out)
{
  const int yy = blockIdx.x;
  const int r0 = (yy < 56 ? yy : yy + 8) * 16;   // skip M home rows [896,1024)
  const int b  = r0 >> 12;
  const int e0 = threadIdx.x * 4;
  __shared__ __align__(16) float sbs[16][36];
  #pragma unroll
  for (int i = 0; i < 2; i++){
    int idx = threadIdx.x + i * 256;           // 512 = 16t * 32k
    int k = idx & 31, t = idx >> 5;
    sbs[t][k] = sb[(size_t)(r0 + t) * K_ + k];
  }
  __syncthreads();
  float4 m4[32];
  const float* mp = Mf + (size_t)b * K_ * D_ + e0;
  #pragma unroll
  for (int k = 0; k < 32; k++) m4[k] = *(const float4*)(mp + (size_t)k * D_);
  float* op = out + (size_t)r0 * D_ + e0;
  #pragma unroll 4
  for (int t = 0; t < 16; ++t){
    float4 o4; o4.x = 0.f; o4.y = 0.f; o4.z = 0.f; o4.w = 0.f;
    const float4* srow = (const float4*)&sbs[t][0];
    #pragma unroll
    for (int j = 0; j < 8; j++){
      float4 s4 = srow[j];
      fma4(o4, s4.x, m4[j * 4 + 0]);
      fma4(o4, s4.y, m4[j * 4 + 1]);
      fma4(o4, s4.z, m4[j * 4 + 2]);
      fma4(o4, s4.w, m4[j * 4 + 3]);
    }
    *(float4*)(op + (size_t)t * D_) = o4;
  }
}

// ---------------------------------------------------------------------------
// k4_tailp: out0 rows [896,1024) — M's home — COLUMN-PARTITIONED.
// grid (64), block 256. Block j owns columns [j*16, j*16+16); race-free.
// ---------------------------------------------------------------------------
__global__ __launch_bounds__(256) void k4_tailp(
    const float* __restrict__ sb, const float* __restrict__ Mf,
    float* __restrict__ out)
{
  __shared__ float sbs[128][33];               // 16.9 KB
  __shared__ __align__(16) float Ms[32][16];   // 2 KB: this block's M columns
  const int j = blockIdx.x;
  #pragma unroll
  for (int i = 0; i < 2; i++){
    int idx = threadIdx.x + i * 256;           // 512 = 32k * 16e
    int k = idx >> 4, e = idx & 15;
    Ms[k][e] = Mf[(size_t)k * D_ + j * 16 + e];
  }
  #pragma unroll
  for (int i = 0; i < 16; i++){
    int idx = threadIdx.x + i * 256;           // 4096 = 128t * 32k
    int k = idx & 31, t = idx >> 5;
    sbs[t][k] = sb[(size_t)(896 + t) * K_ + k];
  }
  __syncthreads();
  const int t  = threadIdx.x >> 1;
  const int c0 = (threadIdx.x & 1) * 8;
  float a0 = 0.f, a1 = 0.f, a2 = 0.f, a3 = 0.f;
  float a4 = 0.f, a5 = 0.f, a6 = 0.f, a7 = 0.f;
  #pragma unroll
  for (int k = 0; k < 32; k++){
    float s = sbs[t][k];
    const float4 m0 = *(const float4*)&Ms[k][c0];
    const float4 m1 = *(const float4*)&Ms[k][c0 + 4];
    a0 = fmaf(s, m0.x, a0); a1 = fmaf(s, m0.y, a1);
    a2 = fmaf(s, m0.z, a2); a3 = fmaf(s, m0.w, a3);
    a4 = fmaf(s, m1.x, a4); a5 = fmaf(s, m1.y, a5);
    a6 = fmaf(s, m1.z, a6); a7 = fmaf(s, m1.w, a7);
  }
  float* op = out + (size_t)(896 + t) * D_ + j * 16 + c0;
  float4 o0; o0.x = a0; o0.y = a1; o0.z = a2; o0.w = a3;
  float4 o1; o1.x = a4; o1.y = a5; o1.z = a6; o1.w = a7;
  *(float4*)(op)     = o0;
  *(float4*)(op + 4) = o1;
}

// ---------------------------------------------------------------------------
extern "C" void kernel_launch(void* const* d_in, const int* in_sizes, int n_in,
                              void* d_out, int out_size, void* d_ws, size_t ws_size,
                              hipStream_t stream)
{
  const float* x    = (const float*)d_in[0];
  const float* sb   = (const float*)d_in[1];
  const float* Wqkv = (const float*)d_in[2];
  const float* Wout = (const float*)d_in[3];
  const float* a_in = (const float*)d_in[4];
  const float* b_in = (const float*)d_in[5];
  const float* W1   = (const float*)d_in[6];
  const float* b1   = (const float*)d_in[7];
  const float* W2   = (const float*)d_in[8];
  const float* b2   = (const float*)d_in[9];
  const float* filt = (const float*)d_in[10];

  float* outF = (float*)d_out;
  float* qkv  = outF + 196608;
  float* u    = outF + 786432;
  float* Mm   = outF + 917504;        // f32 M, out0 rows [896,1024)
  float* S    = outF + 1048576;       // partial slabs (sequentially reused)
  float* S2   = outF + 9699328;       // k1 reduce stage-1 (8 x 135168)
  float* S3   = outF + 5242880;       // gemm2 reduce stage-1 (8 x 131072)
  float* pulse = outF + 16777216;     // (B,H)   f32
  float* resp  = outF + 16777280;     // (B,H,K) f32

  // spectral projection partials (4 c-tiles, b=4, z=64 t-chunks); x read once
  k1_spectral_p<<<dim3(4, 4, 64), 256, 0, stream>>>(x, sb, S);
  // 2-stage reduce: 64 -> 8 -> 1 (+ zero gemm#1's pad rows)
  reduce_g<<<dim3(132, 8), 256, 0, stream>>>((const float4*)S, (float4*)S2,
                                             33792, 8, 33792);
  reduce_zp<<<dim3(192), 256, 0, stream>>>((const float4*)S2, (float4*)outF,
                                           33792, 8, 33792, 49152);

  // qkv GEMM: 16-way split-K partials -> reduce
  gemm_aw_p<<<dim3(48, 3, 16), 256, 0, stream>>>(outF, Wqkv, S, 3072, 64, 589824);
  reduce_z<<<dim3(576), 256, 0, stream>>>((const float4*)S, (float4*)qkv,
                                          147456, 16, 147456);

  k3_small<<<dim3(64), dim3(64), 0, stream>>>(qkv, W1, b1, W2, b2,
                                              filt, a_in, b_in, u,
                                              pulse, resp);

  // out GEMM: 32-way split-K partials -> 2-stage reduce: 32 -> 8 -> 1
  gemm_aw_p<<<dim3(16, 2, 32), 256, 0, stream>>>(u, Wout, S, 1024, 32, 131072);
  reduce_g<<<dim3(128, 8), 256, 0, stream>>>((const float4*)S, (float4*)S3,
                                             32768, 4, 32768);
  reduce_z<<<dim3(128), 256, 0, stream>>>((const float4*)S3, (float4*)Mm,
                                          32768, 8, 32768);

  // All rows except M's home, single launch, 16-row chunks, 4e/thread
  k4_main<<<dim3(1016), 256, 0, stream>>>(sb, Mm, outF);
  // M's home rows, column-partitioned across 64 blocks
  k4_tailp<<<dim3(64), 256, 0, stream>>>(sb, Mm, outF);
}

// Round 10
// 238.417 us; speedup vs baseline: 1.1744x; 1.0955x over previous
//
#include <hip/hip_runtime.h>

// B=4 T=4096 D=1024 H=16 HD=64 K=32 ; inputs f32, OUTPUTS f32.
// NO d_ws usage: all scratch lives inside the 67.1 MB f32 output-0 region.
// Zero atomics: split accumulations write disjoint per-z partial slabs,
// reduced by 2-stage trees (reduce_g then reduce_z/zp).
#define B_ 4
#define T_ 4096
#define D_ 1024
#define H_ 16
#define K_ 32

// ---------------------------------------------------------------------------
// Scratch layout (f32 indices into outF; out0 = floats [0, 16777216)):
//   xs    [0      ,131072)   B*K x 1024   [reduce_zp dst]
//   xbar  [131072 ,135168)   B x 1024     [reduce_zp dst, contiguous w/ xs]
//   pad   [135168 ,196608)   zeros (rows 132..191 of gemm#1 A) [reduce_zp]
//   qkv   [196608 ,786432)   192 x 3072   [reduce_z dst]
//   u     [786432 ,917504)   128 x 1024   [pure write, k3]
//   Mm    [917504 ,1048576)  128 x 1024   [reduce_z dst] = out0 rows [896,1024)
//   S     [1048576,...) partial slabs, sequentially reused:
//     k1 partials   : 64 z-records of 135168 = [1048576, 9699328)
//     k1 stage1     : 8 records of 135168    = [9699328, 10780672)   (S2)
//     gemm1 partials: 16 x 589824            = [1048576, 10485760)
//     gemm2 partials: 32 x 131072            = [1048576, 5242880)
//     gemm2 stage1  : 8 x 131072             = [5242880, 6291456)    (S3)
//   pulse outF[16777216 +64), resp outF[16777280 +2048)
// k1 lesson (r7/r8): dependent rotating prefetch serializes on latency;
// memcpy-shaped burst staging fixed it (53 -> off top-5).
// k4 lesson (r8): register-cached M (128 VGPR) -> VGPR=256 -> 8.6% occupancy
// -> write stream at 1.6 TB/s. Fix: stream M from L2 per-k, hold only the
// 8-row accumulator; occupancy becomes grid-limited.
// ---------------------------------------------------------------------------

__device__ __forceinline__ void fma4(float4& a, float s, const float4& v){
  a.x = fmaf(s, v.x, a.x); a.y = fmaf(s, v.y, a.y);
  a.z = fmaf(s, v.z, a.z); a.w = fmaf(s, v.w, a.w);
}

// reduce_g: dst[g*stride4+i] = sum_{zz<zper} src[(g*zper+zz)*stride4 + i]
__global__ __launch_bounds__(256) void reduce_g(
    const float4* __restrict__ src, float4* __restrict__ dst,
    const int n4, const int zper, const int stride4)
{
  const int g = blockIdx.y;
  int i = blockIdx.x * 256 + threadIdx.x;
  if (i >= n4) return;
  float s0 = 0.f, s1 = 0.f, s2 = 0.f, s3 = 0.f;
  const float4* p = src + (size_t)g * zper * stride4 + i;
  #pragma unroll 8
  for (int zz = 0; zz < zper; ++zz){
    float4 v = p[(size_t)zz * stride4];
    s0 += v.x; s1 += v.y; s2 += v.z; s3 += v.w;
  }
  float4 o; o.x = s0; o.y = s1; o.z = s2; o.w = s3;
  dst[(size_t)g * stride4 + i] = o;
}

// reduce_zp: dst[i] = sum_z src[z*stride4+i] for i<n4; dst[i]=0 for
// n4<=i<total4 (zeroes gemm#1's pad rows).
__global__ __launch_bounds__(256) void reduce_zp(
    const float4* __restrict__ src, float4* __restrict__ dst,
    const int n4, const int z, const int stride4, const int total4)
{
  int i = blockIdx.x * 256 + threadIdx.x;
  if (i >= total4) return;
  if (i >= n4){
    float4 zv; zv.x = 0.f; zv.y = 0.f; zv.z = 0.f; zv.w = 0.f;
    dst[i] = zv; return;
  }
  float s0 = 0.f, s1 = 0.f, s2 = 0.f, s3 = 0.f;
  const float4* p = src + i;
  #pragma unroll 8
  for (int zz = 0; zz < z; ++zz){
    float4 v = p[(size_t)zz * stride4];
    s0 += v.x; s1 += v.y; s2 += v.z; s3 += v.w;
  }
  float4 o; o.x = s0; o.y = s1; o.z = s2; o.w = s3;
  dst[i] = o;
}

__global__ __launch_bounds__(256) void reduce_z(
    const float4* __restrict__ src, float4* __restrict__ dst,
    const int n4, const int z, const int stride4)
{
  int i = blockIdx.x * 256 + threadIdx.x;
  if (i >= n4) return;
  float s0 = 0.f, s1 = 0.f, s2 = 0.f, s3 = 0.f;
  const float4* p = src + i;
  #pragma unroll 8
  for (int zz = 0; zz < z; ++zz){
    float4 v = p[(size_t)zz * stride4];
    s0 += v.x; s1 += v.y; s2 += v.z; s3 += v.w;
  }
  float4 o; o.x = s0; o.y = s1; o.z = s2; o.w = s3;
  dst[i] = o;
}

// ---------------------------------------------------------------------------
// K1 (partials): XPz[b][k][c] = sum_{t in chunk z} sb[b,t,k]*x[b,t,c]
//                XPz[xbar][b][c] = sum_{t in chunk z} x[b,t,c]
// grid (4 c-tiles, B, 64 z), block 256. Full K=32 per block; x read ONCE.
// STAGE: 16 independent float4 loads/thread (memcpy-shaped) into a 64t x
// 256c LDS tile + sb tile; barrier; COMPUTE: x from LDS (b128) + 2
// wave-uniform sbs broadcasts + 32 FMA per t.
// LDS = 65536 + 9216 = 74752 B -> 2 blocks/CU.
// ---------------------------------------------------------------------------
__global__ __launch_bounds__(256) void k1_spectral_p(
    const float* __restrict__ x, const float* __restrict__ sb,
    float* __restrict__ XP)
{
  const int ct = blockIdx.x;
  const int b  = blockIdx.y;
  const int zz = blockIdx.z;
  const int t0 = zz * 64;
  const int cs = threadIdx.x & 63;
  const int kg = threadIdx.x >> 6;          // == wave id
  __shared__ __align__(16) float4 xt[4096];   // 64t x 64 float4 (256 c) 64KB
  __shared__ __align__(16) float sbs[64][36]; // 9.2KB
  #pragma unroll
  for (int i = 0; i < 8; i++){
    int idx = threadIdx.x + i * 256;        // 2048 = 64t * 32k
    int t = idx >> 5, kk = idx & 31;
    sbs[t][kk] = sb[(size_t)(b * T_ + t0 + t) * K_ + kk];
  }
  const float4* xg = (const float4*)(x + (size_t)(b * T_ + t0) * D_ + ct * 256);
  float4 rv[16];
  #pragma unroll
  for (int j = 0; j < 16; j++){
    int idx = threadIdx.x + j * 256;        // 4096 float4 = 64t * 64cq
    int t = idx >> 6, cq = idx & 63;
    rv[j] = xg[(size_t)t * 256 + cq];
  }
  #pragma unroll
  for (int j = 0; j < 16; j++) xt[threadIdx.x + j * 256] = rv[j];
  __syncthreads();

  float4 acc[8];
  #pragma unroll
  for (int k = 0; k < 8; k++){ acc[k].x = 0.f; acc[k].y = 0.f;
                               acc[k].z = 0.f; acc[k].w = 0.f; }
  float4 am; am.x = 0.f; am.y = 0.f; am.z = 0.f; am.w = 0.f;
  #pragma unroll 4
  for (int t = 0; t < 64; ++t){
    float4 xv = xt[t * 64 + cs];
    if (kg == 0){ am.x += xv.x; am.y += xv.y; am.z += xv.z; am.w += xv.w; }
    const float4* srow = (const float4*)&sbs[t][kg * 8];  // wave-uniform
    float4 s0 = srow[0], s1 = srow[1];
    fma4(acc[0], s0.x, xv); fma4(acc[1], s0.y, xv);
    fma4(acc[2], s0.z, xv); fma4(acc[3], s0.w, xv);
    fma4(acc[4], s1.x, xv); fma4(acc[5], s1.y, xv);
    fma4(acc[6], s1.z, xv); fma4(acc[7], s1.w, xv);
  }
  const int c = ct * 256 + cs * 4;
  float* o = XP + (size_t)zz * 135168 + (size_t)(b * K_ + kg * 8) * D_ + c;
  #pragma unroll
  for (int k = 0; k < 8; k++) *(float4*)(o + (size_t)k * D_) = acc[k];
  if (kg == 0)
    *(float4*)(XP + (size_t)zz * 135168 + 131072 + b * D_ + c) = am;
}

// ---------------------------------------------------------------------------
// gemm_aw_p: Cp[z][m][n] = sum_{c in split} A[m][c]*W[n][c]; PURE STORES.
// grid (N/64, M/64, csplit), block 256; 64x64 tile; c-chunk 32 (17.4 KB LDS).
// Register-staged double buffer.
// ---------------------------------------------------------------------------
__global__ __launch_bounds__(256) void gemm_aw_p(
    const float* __restrict__ A, const float* __restrict__ W,
    float* __restrict__ Cp, const int N, const int cPerSplit, const int MN)
{
  __shared__ __align__(16) float As[32][68];
  __shared__ __align__(16) float Ws[32][68];
  const int nt = blockIdx.x, mt = blockIdx.y;
  const int cbase = blockIdx.z * cPerSplit;
  const int tx = threadIdx.x & 15, ty = threadIdx.x >> 4;
  const int sc = threadIdx.x & 31, sr = threadIdx.x >> 5;  // staging coords
  float acc[4][4];
  #pragma unroll
  for (int i = 0; i < 4; i++)
    #pragma unroll
    for (int j = 0; j < 4; j++) acc[i][j] = 0.f;

  float ra[8], rw[8];
  const float* Ap = A + (size_t)(mt * 64 + sr) * 1024 + cbase + sc;
  const float* Wp = W + (size_t)(nt * 64 + sr) * 1024 + cbase + sc;
  #pragma unroll
  for (int i = 0; i < 8; i++){ ra[i] = Ap[(size_t)(i * 8) * 1024];
                               rw[i] = Wp[(size_t)(i * 8) * 1024]; }
  #pragma unroll
  for (int i = 0; i < 8; i++){ As[sc][sr + i * 8] = ra[i];
                               Ws[sc][sr + i * 8] = rw[i]; }
  __syncthreads();

  for (int cc = 32; cc < cPerSplit; cc += 32){
    #pragma unroll
    for (int i = 0; i < 8; i++){ ra[i] = Ap[(size_t)(i * 8) * 1024 + cc];
                                 rw[i] = Wp[(size_t)(i * 8) * 1024 + cc]; }
    #pragma unroll 4
    for (int c = 0; c < 32; ++c){
      const float4 a4 = *(const float4*)&As[c][ty * 4];
      const float4 w4 = *(const float4*)&Ws[c][tx * 4];
      acc[0][0] = fmaf(a4.x, w4.x, acc[0][0]);
      acc[0][1] = fmaf(a4.x, w4.y, acc[0][1]);
      acc[0][2] = fmaf(a4.x, w4.z, acc[0][2]);
      acc[0][3] = fmaf(a4.x, w4.w, acc[0][3]);
      acc[1][0] = fmaf(a4.y, w4.x, acc[1][0]);
      acc[1][1] = fmaf(a4.y, w4.y, acc[1][1]);
      acc[1][2] = fmaf(a4.y, w4.z, acc[1][2]);
      acc[1][3] = fmaf(a4.y, w4.w, acc[1][3]);
      acc[2][0] = fmaf(a4.z, w4.x, acc[2][0]);
      acc[2][1] = fmaf(a4.z, w4.y, acc[2][1]);
      acc[2][2] = fmaf(a4.z, w4.z, acc[2][2]);
      acc[2][3] = fmaf(a4.z, w4.w, acc[2][3]);
      acc[3][0] = fmaf(a4.w, w4.x, acc[3][0]);
      acc[3][1] = fmaf(a4.w, w4.y, acc[3][1]);
      acc[3][2] = fmaf(a4.w, w4.z, acc[3][2]);
      acc[3][3] = fmaf(a4.w, w4.w, acc[3][3]);
    }
    __syncthreads();
    #pragma unroll
    for (int i = 0; i < 8; i++){ As[sc][sr + i * 8] = ra[i];
                                 Ws[sc][sr + i * 8] = rw[i]; }
    __syncthreads();
  }
  #pragma unroll 4
  for (int c = 0; c < 32; ++c){
    const float4 a4 = *(const float4*)&As[c][ty * 4];
    const float4 w4 = *(const float4*)&Ws[c][tx * 4];
    acc[0][0] = fmaf(a4.x, w4.x, acc[0][0]);
    acc[0][1] = fmaf(a4.x, w4.y, acc[0][1]);
    acc[0][2] = fmaf(a4.x, w4.z, acc[0][2]);
    acc[0][3] = fmaf(a4.x, w4.w, acc[0][3]);
    acc[1][0] = fmaf(a4.y, w4.x, acc[1][0]);
    acc[1][1] = fmaf(a4.y, w4.y, acc[1][1]);
    acc[1][2] = fmaf(a4.y, w4.z, acc[1][2]);
    acc[1][3] = fmaf(a4.y, w4.w, acc[1][3]);
    acc[2][0] = fmaf(a4.z, w4.x, acc[2][0]);
    acc[2][1] = fmaf(a4.z, w4.y, acc[2][1]);
    acc[2][2] = fmaf(a4.z, w4.z, acc[2][2]);
    acc[2][3] = fmaf(a4.z, w4.w, acc[2][3]);
    acc[3][0] = fmaf(a4.w, w4.x, acc[3][0]);
    acc[3][1] = fmaf(a4.w, w4.y, acc[3][1]);
    acc[3][2] = fmaf(a4.w, w4.z, acc[3][2]);
    acc[3][3] = fmaf(a4.w, w4.w, acc[3][3]);
  }
  float* cp = Cp + (size_t)blockIdx.z * MN;
  #pragma unroll
  for (int i = 0; i < 4; i++){
    float4 o; o.x = acc[i][0]; o.y = acc[i][1]; o.z = acc[i][2]; o.w = acc[i][3];
    *(float4*)(cp + (size_t)(mt * 64 + ty * 4 + i) * N + nt * 64 + tx * 4) = o;
  }
}

// ---------------------------------------------------------------------------
// K3: pulse (qkv row 128+b = xbar@Wqkv.T), attn_spec, soliton ODE, u=resp*v_spec
// grid 64 blocks (b*16+h), 64 threads. All outputs f32.
// ---------------------------------------------------------------------------
__global__ __launch_bounds__(64) void k3_small(
    const float* __restrict__ qkvC,
    const float* __restrict__ W1, const float* __restrict__ b1,
    const float* __restrict__ W2, const float* __restrict__ b2,
    const float* __restrict__ filt,
    const float* __restrict__ a_in, const float* __restrict__ b_in,
    float* __restrict__ u, float* __restrict__ out_pulse,
    float* __restrict__ out_resp)
{
  const int b = blockIdx.x >> 4, h = blockIdx.x & 15;
  const int d = threadIdx.x;
  __shared__ float qm[64];
  __shared__ float h1s[32];
  __shared__ float rsp[32];
  qm[d] = qkvC[(size_t)(128 + b) * 3072 + h * 64 + d] * (1.0f / 4096.0f);
  __syncthreads();
  if (d < 32){
    float z = b1[d];
    for (int j = 0; j < 64; j++) z = fmaf(qm[j], W1[d * 64 + j], z);
    h1s[d] = z / (1.0f + __expf(-z));             // silu
  }
  __syncthreads();
  if (d == 0){
    float z2 = b2[0];
    for (int j = 0; j < 32; j++) z2 = fmaf(h1s[j], W2[j], z2);
    out_pulse[b * H_ + h] = 4.0f + log1pf(__expf(z2));  // PULSE_BASE+softplus
  }
  if (d < 32){
    const int k = d;
    const float* qrow = qkvC + (size_t)(b * K_ + k) * 3072 + h * 64;
    const float* krow = qrow + 1024;
    float s = 0.f;
    for (int j = 0; j < 64; j++) s = fmaf(qrow[j], krow[j], s);
    float fg = 1.0f / (1.0f + __expf(-filt[h * 32 + k]));
    s = s * 0.125f * fg;                          // /sqrt(64)*sigmoid(filter)
    float av = a_in[0], bv = b_in[0];
    float sc = fmaxf(fabsf(s), 1e-6f);
    float sn = s / sc;
    float I  = (fabsf(s) > 0.5f) ? sn : 0.1f * sn;
    float v = 0.f, w = 0.f;
    #pragma unroll
    for (int it = 0; it < 5; ++it){
      float dv = v - v * v * v * (1.0f / 3.0f) - w + I;
      float dw = (v + av - bv * w) * 10.0f;       // /TAU
      v = fminf(fmaxf(v + 0.2f * dv, -3.0f), 3.0f);
      w = fminf(fmaxf(w + 0.2f * dw, -3.0f), 3.0f);
    }
    float r = v * sc;
    rsp[k] = r;
    out_resp[(b * H_ + h) * K_ + k] = r;
  }
  __syncthreads();
  for (int k = 0; k < 32; k++){
    u[(size_t)(b * K_ + k) * D_ + h * 64 + d] =
        rsp[k] * qkvC[(size_t)(b * K_ + k) * 3072 + 2048 + h * 64 + d];
  }
}

// ---------------------------------------------------------------------------
// k4_main: all out0 rows EXCEPT [896,1024); 32-row chunks x 256-e tiles.
// grid (4, 508), block 256 (4 waves). Wave w owns t-rows [w*8, w*8+8);
// lane owns e-quad. M is STREAMED from L2 per-k (no register cache);
// only acc4[8] (32 VGPR) is live -> high occupancy, write-BW-bound.
// sbsT transposed tile: per k, the 8 t-coeffs = 2 wave-uniform b128 reads.
// ---------------------------------------------------------------------------
__global__ __launch_bounds__(256) void k4_main(
    const float* __restrict__ sb, const float* __restrict__ Mf,
    float* __restrict__ out)
{
  const int ct = blockIdx.x;
  const int yy = blockIdx.y;
  const int r0 = (yy < 28 ? yy : yy + 4) * 32;   // skip M home rows [896,1024)
  const int b  = r0 >> 12;
  const int w  = threadIdx.x >> 6;               // wave id: t-rows [w*8,w*8+8)
  const int ls = threadIdx.x & 63;               // lane: e-quad
  __shared__ __align__(16) float sbsT[32][36];   // [k][t], rows 16B-aligned
  #pragma unroll
  for (int i = 0; i < 4; i++){
    int idx = threadIdx.x + i * 256;             // 1024 = 32t * 32k
    int t = idx >> 5, k = idx & 31;
    sbsT[k][t] = sb[(size_t)(r0 + t) * K_ + k];
  }
  __syncthreads();
  float4 acc[8];
  #pragma unroll
  for (int i = 0; i < 8; i++){ acc[i].x = 0.f; acc[i].y = 0.f;
                               acc[i].z = 0.f; acc[i].w = 0.f; }
  const float4* Mg = (const float4*)(Mf + (size_t)b * K_ * D_);
  const int eq = ct * 64 + ls;                   // e-quad within D (256 f4)
  #pragma unroll 8
  for (int k = 0; k < 32; ++k){
    float4 mv = Mg[(size_t)k * 256 + eq];        // L2-hot stream
    const float4* srow = (const float4*)&sbsT[k][w * 8];  // wave-uniform
    float4 s0 = srow[0], s1 = srow[1];
    fma4(acc[0], s0.x, mv); fma4(acc[1], s0.y, mv);
    fma4(acc[2], s0.z, mv); fma4(acc[3], s0.w, mv);
    fma4(acc[4], s1.x, mv); fma4(acc[5], s1.y, mv);
    fma4(acc[6], s1.z, mv); fma4(acc[7], s1.w, mv);
  }
  float* op = out + (size_t)(r0 + w * 8) * D_ + eq * 4;
  #pragma unroll
  for (int i = 0; i < 8; i++)
    *(float4*)(op + (size_t)i * D_) = acc[i];
}

// ---------------------------------------------------------------------------
// k4_tailp: out0 rows [896,1024) — M's home — COLUMN-PARTITIONED.
// grid (64), block 256. Block j owns columns [j*16, j*16+16); race-free.
// ---------------------------------------------------------------------------
__global__ __launch_bounds__(256) void k4_tailp(
    const float* __restrict__ sb, const float* __restrict__ Mf,
    float* __restrict__ out)
{
  __shared__ float sbs[128][33];               // 16.9 KB
  __shared__ __align__(16) float Ms[32][16];   // 2 KB: this block's M columns
  const int j = blockIdx.x;
  #pragma unroll
  for (int i = 0; i < 2; i++){
    int idx = threadIdx.x + i * 256;           // 512 = 32k * 16e
    int k = idx >> 4, e = idx & 15;
    Ms[k][e] = Mf[(size_t)k * D_ + j * 16 + e];
  }
  #pragma unroll
  for (int i = 0; i < 16; i++){
    int idx = threadIdx.x + i * 256;           // 4096 = 128t * 32k
    int k = idx & 31, t = idx >> 5;
    sbs[t][k] = sb[(size_t)(896 + t) * K_ + k];
  }
  __syncthreads();
  const int t  = threadIdx.x >> 1;
  const int c0 = (threadIdx.x & 1) * 8;
  float a0 = 0.f, a1 = 0.f, a2 = 0.f, a3 = 0.f;
  float a4 = 0.f, a5 = 0.f, a6 = 0.f, a7 = 0.f;
  #pragma unroll
  for (int k = 0; k < 32; k++){
    float s = sbs[t][k];
    const float4 m0 = *(const float4*)&Ms[k][c0];
    const float4 m1 = *(const float4*)&Ms[k][c0 + 4];
    a0 = fmaf(s, m0.x, a0); a1 = fmaf(s, m0.y, a1);
    a2 = fmaf(s, m0.z, a2); a3 = fmaf(s, m0.w, a3);
    a4 = fmaf(s, m1.x, a4); a5 = fmaf(s, m1.y, a5);
    a6 = fmaf(s, m1.z, a6); a7 = fmaf(s, m1.w, a7);
  }
  float* op = out + (size_t)(896 + t) * D_ + j * 16 + c0;
  float4 o0; o0.x = a0; o0.y = a1; o0.z = a2; o0.w = a3;
  float4 o1; o1.x = a4; o1.y = a5; o1.z = a6; o1.w = a7;
  *(float4*)(op)     = o0;
  *(float4*)(op + 4) = o1;
}

// ---------------------------------------------------------------------------
extern "C" void kernel_launch(void* const* d_in, const int* in_sizes, int n_in,
                              void* d_out, int out_size, void* d_ws, size_t ws_size,
                              hipStream_t stream)
{
  const float* x    = (const float*)d_in[0];
  const float* sb   = (const float*)d_in[1];
  const float* Wqkv = (const float*)d_in[2];
  const float* Wout = (const float*)d_in[3];
  const float* a_in = (const float*)d_in[4];
  const float* b_in = (const float*)d_in[5];
  const float* W1   = (const float*)d_in[6];
  const float* b1   = (const float*)d_in[7];
  const float* W2   = (const float*)d_in[8];
  const float* b2   = (const float*)d_in[9];
  const float* filt = (const float*)d_in[10];

  float* outF = (float*)d_out;
  float* qkv  = outF + 196608;
  float* u    = outF + 786432;
  float* Mm   = outF + 917504;        // f32 M, out0 rows [896,1024)
  float* S    = outF + 1048576;       // partial slabs (sequentially reused)
  float* S2   = outF + 9699328;       // k1 reduce stage-1 (8 x 135168)
  float* S3   = outF + 5242880;       // gemm2 reduce stage-1 (8 x 131072)
  float* pulse = outF + 16777216;     // (B,H)   f32
  float* resp  = outF + 16777280;     // (B,H,K) f32

  // spectral projection partials (4 c-tiles, b=4, z=64 t-chunks); x read once
  k1_spectral_p<<<dim3(4, 4, 64), 256, 0, stream>>>(x, sb, S);
  // 2-stage reduce: 64 -> 8 -> 1 (+ zero gemm#1's pad rows)
  reduce_g<<<dim3(132, 8), 256, 0, stream>>>((const float4*)S, (float4*)S2,
                                             33792, 8, 33792);
  reduce_zp<<<dim3(192), 256, 0, stream>>>((const float4*)S2, (float4*)outF,
                                           33792, 8, 33792, 49152);

  // qkv GEMM: 16-way split-K partials -> reduce
  gemm_aw_p<<<dim3(48, 3, 16), 256, 0, stream>>>(outF, Wqkv, S, 3072, 64, 589824);
  reduce_z<<<dim3(576), 256, 0, stream>>>((const float4*)S, (float4*)qkv,
                                          147456, 16, 147456);

  k3_small<<<dim3(64), dim3(64), 0, stream>>>(qkv, W1, b1, W2, b2,
                                              filt, a_in, b_in, u,
                                              pulse, resp);

  // out GEMM: 32-way split-K partials -> 2-stage reduce: 32 -> 8 -> 1
  gemm_aw_p<<<dim3(16, 2, 32), 256, 0, stream>>>(u, Wout, S, 1024, 32, 131072);
  reduce_g<<<dim3(128, 8), 256, 0, stream>>>((const float4*)S, (float4*)S3,
                                             32768, 4, 32768);
  reduce_z<<<dim3(128), 256, 0, stream>>>((const float4*)S3, (float4*)Mm,
                                          32768, 8, 32768);

  // All rows except M's home: 32-row chunks x 4 e-tiles, M streamed from L2
  k4_main<<<dim3(4, 508), 256, 0, stream>>>(sb, Mm, outF);
  // M's home rows, column-partitioned across 64 blocks
  k4_tailp<<<dim3(64), 256, 0, stream>>>(sb, Mm, outF);
}

// Round 11
// 231.417 us; speedup vs baseline: 1.2100x; 1.0302x over previous
//
#include <hip/hip_runtime.h>

// B=4 T=4096 D=1024 H=16 HD=64 K=32 ; inputs f32, OUTPUTS f32.
// NO d_ws usage: all scratch lives inside the 67.1 MB f32 output-0 region.
// Zero atomics: split accumulations write disjoint per-z partial slabs,
// reduced by 2-stage trees (reduce_g then reduce_z/zp).
#define B_ 4
#define T_ 4096
#define D_ 1024
#define H_ 16
#define K_ 32

// ---------------------------------------------------------------------------
// Scratch layout (f32 indices into outF; out0 = floats [0, 16777216)):
//   xs    [0      ,131072)   B*K x 1024   [reduce_zp dst]
//   xbar  [131072 ,135168)   B x 1024     [reduce_zp dst, contiguous w/ xs]
//   pad   [135168 ,196608)   zeros (rows 132..191 of gemm#1 A) [reduce_zp]
//   qkv   [196608 ,786432)   192 x 3072   [reduce_z dst]
//   u     [786432 ,917504)   128 x 1024   [pure write, k3]
//   Mm    [917504 ,1048576)  128 x 1024   [reduce_z dst] = out0 rows [896,1024)
//   S     [1048576,...) partial slabs, sequentially reused:
//     k1 partials   : 64 z-records of 135168 = [1048576, 9699328)
//     k1 stage1     : 8 records of 135168    = [9699328, 10780672)   (S2)
//     gemm1 partials: 16 x 589824            = [1048576, 10485760)
//     gemm2 partials: 16 x 131072            = [1048576, 3145728)
//     gemm2 stage1  : 4 x 131072             = [5242880, 5767168)    (S3)
//   pulse outF[16777216 +64), resp outF[16777280 +2048)
// Lessons: (r7/r8) dependent rotating prefetch serializes on latency -> use
// memcpy-shaped burst staging. (r8) fat register caches kill occupancy ->
// stream L2-hot data, hold only accumulators. (r4) LDS cost ~ bytes
// delivered to RF, not instruction count -> raise FMA:LDS-byte ratio.
// (r10) gemm1 was LDS-volume-bound (2B/FMA) -> 4x8 thread tile (1.5B/FMA).
// ---------------------------------------------------------------------------

__device__ __forceinline__ void fma4(float4& a, float s, const float4& v){
  a.x = fmaf(s, v.x, a.x); a.y = fmaf(s, v.y, a.y);
  a.z = fmaf(s, v.z, a.z); a.w = fmaf(s, v.w, a.w);
}

// reduce_g: dst[g*stride4+i] = sum_{zz<zper} src[(g*zper+zz)*stride4 + i]
__global__ __launch_bounds__(256) void reduce_g(
    const float4* __restrict__ src, float4* __restrict__ dst,
    const int n4, const int zper, const int stride4)
{
  const int g = blockIdx.y;
  int i = blockIdx.x * 256 + threadIdx.x;
  if (i >= n4) return;
  float s0 = 0.f, s1 = 0.f, s2 = 0.f, s3 = 0.f;
  const float4* p = src + (size_t)g * zper * stride4 + i;
  #pragma unroll 8
  for (int zz = 0; zz < zper; ++zz){
    float4 v = p[(size_t)zz * stride4];
    s0 += v.x; s1 += v.y; s2 += v.z; s3 += v.w;
  }
  float4 o; o.x = s0; o.y = s1; o.z = s2; o.w = s3;
  dst[(size_t)g * stride4 + i] = o;
}

// reduce_zp: dst[i] = sum_z src[z*stride4+i] for i<n4; dst[i]=0 for
// n4<=i<total4 (zeroes gemm#1's pad rows).
__global__ __launch_bounds__(256) void reduce_zp(
    const float4* __restrict__ src, float4* __restrict__ dst,
    const int n4, const int z, const int stride4, const int total4)
{
  int i = blockIdx.x * 256 + threadIdx.x;
  if (i >= total4) return;
  if (i >= n4){
    float4 zv; zv.x = 0.f; zv.y = 0.f; zv.z = 0.f; zv.w = 0.f;
    dst[i] = zv; return;
  }
  float s0 = 0.f, s1 = 0.f, s2 = 0.f, s3 = 0.f;
  const float4* p = src + i;
  #pragma unroll 8
  for (int zz = 0; zz < z; ++zz){
    float4 v = p[(size_t)zz * stride4];
    s0 += v.x; s1 += v.y; s2 += v.z; s3 += v.w;
  }
  float4 o; o.x = s0; o.y = s1; o.z = s2; o.w = s3;
  dst[i] = o;
}

__global__ __launch_bounds__(256) void reduce_z(
    const float4* __restrict__ src, float4* __restrict__ dst,
    const int n4, const int z, const int stride4)
{
  int i = blockIdx.x * 256 + threadIdx.x;
  if (i >= n4) return;
  float s0 = 0.f, s1 = 0.f, s2 = 0.f, s3 = 0.f;
  const float4* p = src + i;
  #pragma unroll 8
  for (int zz = 0; zz < z; ++zz){
    float4 v = p[(size_t)zz * stride4];
    s0 += v.x; s1 += v.y; s2 += v.z; s3 += v.w;
  }
  float4 o; o.x = s0; o.y = s1; o.z = s2; o.w = s3;
  dst[i] = o;
}

// ---------------------------------------------------------------------------
// K1 (partials): XPz[b][k][c] = sum_{t in chunk z} sb[b,t,k]*x[b,t,c]
//                XPz[xbar][b][c] = sum_{t in chunk z} x[b,t,c]
// grid (4 c-tiles, B, 64 z), block 256. Full K=32 per block; x read ONCE.
// STAGE: 16 independent float4 loads/thread (memcpy-shaped) into a 64t x
// 256c LDS tile + sb tile; barrier; COMPUTE: x from LDS (b128) + 2
// wave-uniform sbs broadcasts + 32 FMA per t.
// LDS = 65536 + 9216 = 74752 B -> 2 blocks/CU.
// ---------------------------------------------------------------------------
__global__ __launch_bounds__(256) void k1_spectral_p(
    const float* __restrict__ x, const float* __restrict__ sb,
    float* __restrict__ XP)
{
  const int ct = blockIdx.x;
  const int b  = blockIdx.y;
  const int zz = blockIdx.z;
  const int t0 = zz * 64;
  const int cs = threadIdx.x & 63;
  const int kg = threadIdx.x >> 6;          // == wave id
  __shared__ __align__(16) float4 xt[4096];   // 64t x 64 float4 (256 c) 64KB
  __shared__ __align__(16) float sbs[64][36]; // 9.2KB
  #pragma unroll
  for (int i = 0; i < 8; i++){
    int idx = threadIdx.x + i * 256;        // 2048 = 64t * 32k
    int t = idx >> 5, kk = idx & 31;
    sbs[t][kk] = sb[(size_t)(b * T_ + t0 + t) * K_ + kk];
  }
  const float4* xg = (const float4*)(x + (size_t)(b * T_ + t0) * D_ + ct * 256);
  float4 rv[16];
  #pragma unroll
  for (int j = 0; j < 16; j++){
    int idx = threadIdx.x + j * 256;        // 4096 float4 = 64t * 64cq
    int t = idx >> 6, cq = idx & 63;
    rv[j] = xg[(size_t)t * 256 + cq];
  }
  #pragma unroll
  for (int j = 0; j < 16; j++) xt[threadIdx.x + j * 256] = rv[j];
  __syncthreads();

  float4 acc[8];
  #pragma unroll
  for (int k = 0; k < 8; k++){ acc[k].x = 0.f; acc[k].y = 0.f;
                               acc[k].z = 0.f; acc[k].w = 0.f; }
  float4 am; am.x = 0.f; am.y = 0.f; am.z = 0.f; am.w = 0.f;
  #pragma unroll 4
  for (int t = 0; t < 64; ++t){
    float4 xv = xt[t * 64 + cs];
    if (kg == 0){ am.x += xv.x; am.y += xv.y; am.z += xv.z; am.w += xv.w; }
    const float4* srow = (const float4*)&sbs[t][kg * 8];  // wave-uniform
    float4 s0 = srow[0], s1 = srow[1];
    fma4(acc[0], s0.x, xv); fma4(acc[1], s0.y, xv);
    fma4(acc[2], s0.z, xv); fma4(acc[3], s0.w, xv);
    fma4(acc[4], s1.x, xv); fma4(acc[5], s1.y, xv);
    fma4(acc[6], s1.z, xv); fma4(acc[7], s1.w, xv);
  }
  const int c = ct * 256 + cs * 4;
  float* o = XP + (size_t)zz * 135168 + (size_t)(b * K_ + kg * 8) * D_ + c;
  #pragma unroll
  for (int k = 0; k < 8; k++) *(float4*)(o + (size_t)k * D_) = acc[k];
  if (kg == 0)
    *(float4*)(XP + (size_t)zz * 135168 + 131072 + b * D_ + c) = am;
}

// ---------------------------------------------------------------------------
// gemm_qkv: qkv GEMM partials. Cp[z][m][n] = sum_{c in 64-chunk} A[m][c]*W[n][c]
// A = 192x1024 (xs;xbar;pad), W = Wqkv 3072x1024. grid (24, 3, 16), block 256.
// 64m x 128n block tile, 4m x 8n thread tile (1.5 B LDS / FMA vs old 2.0).
// SINGLE 64-c chunk: memcpy-shaped staging (16+32 indep loads) -> 1 barrier
// -> 64-c FMA loop -> float4 stores. W read as two half-tiles (tx*4, 64+tx*4)
// so b128 LDS reads stay 2-way bank-aliased (free). LDS 51.2KB -> 3 blk/CU.
// ---------------------------------------------------------------------------
__global__ __launch_bounds__(256) void gemm_qkv(
    const float* __restrict__ A, const float* __restrict__ W,
    float* __restrict__ Cp)
{
  __shared__ __align__(16) float As[64][68];   // [c][m] 17.4 KB
  __shared__ __align__(16) float Ws[64][132];  // [c][n] 33.8 KB
  const int nt = blockIdx.x, mt = blockIdx.y;
  const int cb = blockIdx.z * 64;
  const int sc = threadIdx.x & 63, sr = threadIdx.x >> 6;
  {
    const float* Ap = A + (size_t)(mt * 64 + sr) * 1024 + cb + sc;
    float r[16];
    #pragma unroll
    for (int i = 0; i < 16; i++) r[i] = Ap[(size_t)(i * 4) * 1024];
    #pragma unroll
    for (int i = 0; i < 16; i++) As[sc][sr + i * 4] = r[i];
  }
  {
    const float* Wp = W + (size_t)(nt * 128 + sr) * 1024 + cb + sc;
    float r[32];
    #pragma unroll
    for (int i = 0; i < 32; i++) r[i] = Wp[(size_t)(i * 4) * 1024];
    #pragma unroll
    for (int i = 0; i < 32; i++) Ws[sc][sr + i * 4] = r[i];
  }
  __syncthreads();
  const int tx = threadIdx.x & 15, ty = threadIdx.x >> 4;
  float4 acc[4][2];
  #pragma unroll
  for (int i = 0; i < 4; i++)
    #pragma unroll
    for (int j = 0; j < 2; j++){ acc[i][j].x = 0.f; acc[i][j].y = 0.f;
                                 acc[i][j].z = 0.f; acc[i][j].w = 0.f; }
  #pragma unroll 8
  for (int c = 0; c < 64; ++c){
    const float4 a4 = *(const float4*)&As[c][ty * 4];
    const float4 w0 = *(const float4*)&Ws[c][tx * 4];
    const float4 w1 = *(const float4*)&Ws[c][64 + tx * 4];
    fma4(acc[0][0], a4.x, w0); fma4(acc[0][1], a4.x, w1);
    fma4(acc[1][0], a4.y, w0); fma4(acc[1][1], a4.y, w1);
    fma4(acc[2][0], a4.z, w0); fma4(acc[2][1], a4.z, w1);
    fma4(acc[3][0], a4.w, w0); fma4(acc[3][1], a4.w, w1);
  }
  float* cp = Cp + (size_t)blockIdx.z * 589824;
  #pragma unroll
  for (int i = 0; i < 4; i++){
    float* row = cp + (size_t)(mt * 64 + ty * 4 + i) * 3072 + nt * 128;
    *(float4*)(row + tx * 4)      = acc[i][0];
    *(float4*)(row + 64 + tx * 4) = acc[i][1];
  }
}

// ---------------------------------------------------------------------------
// gemm_aw_p (used for gemm#2): Cp[z][m][n] = sum_{c in split} A[m][c]*W[n][c]
// grid (N/64, M/64, csplit), block 256; 64x64 tile; c-chunk 32; reg dbuf.
// ---------------------------------------------------------------------------
__global__ __launch_bounds__(256) void gemm_aw_p(
    const float* __restrict__ A, const float* __restrict__ W,
    float* __restrict__ Cp, const int N, const int cPerSplit, const int MN)
{
  __shared__ __align__(16) float As[32][68];
  __shared__ __align__(16) float Ws[32][68];
  const int nt = blockIdx.x, mt = blockIdx.y;
  const int cbase = blockIdx.z * cPerSplit;
  const int tx = threadIdx.x & 15, ty = threadIdx.x >> 4;
  const int sc = threadIdx.x & 31, sr = threadIdx.x >> 5;  // staging coords
  float acc[4][4];
  #pragma unroll
  for (int i = 0; i < 4; i++)
    #pragma unroll
    for (int j = 0; j < 4; j++) acc[i][j] = 0.f;

  float ra[8], rw[8];
  const float* Ap = A + (size_t)(mt * 64 + sr) * 1024 + cbase + sc;
  const float* Wp = W + (size_t)(nt * 64 + sr) * 1024 + cbase + sc;
  #pragma unroll
  for (int i = 0; i < 8; i++){ ra[i] = Ap[(size_t)(i * 8) * 1024];
                               rw[i] = Wp[(size_t)(i * 8) * 1024]; }
  #pragma unroll
  for (int i = 0; i < 8; i++){ As[sc][sr + i * 8] = ra[i];
                               Ws[sc][sr + i * 8] = rw[i]; }
  __syncthreads();

  for (int cc = 32; cc < cPerSplit; cc += 32){
    #pragma unroll
    for (int i = 0; i < 8; i++){ ra[i] = Ap[(size_t)(i * 8) * 1024 + cc];
                                 rw[i] = Wp[(size_t)(i * 8) * 1024 + cc]; }
    #pragma unroll 4
    for (int c = 0; c < 32; ++c){
      const float4 a4 = *(const float4*)&As[c][ty * 4];
      const float4 w4 = *(const float4*)&Ws[c][tx * 4];
      acc[0][0] = fmaf(a4.x, w4.x, acc[0][0]);
      acc[0][1] = fmaf(a4.x, w4.y, acc[0][1]);
      acc[0][2] = fmaf(a4.x, w4.z, acc[0][2]);
      acc[0][3] = fmaf(a4.x, w4.w, acc[0][3]);
      acc[1][0] = fmaf(a4.y, w4.x, acc[1][0]);
      acc[1][1] = fmaf(a4.y, w4.y, acc[1][1]);
      acc[1][2] = fmaf(a4.y, w4.z, acc[1][2]);
      acc[1][3] = fmaf(a4.y, w4.w, acc[1][3]);
      acc[2][0] = fmaf(a4.z, w4.x, acc[2][0]);
      acc[2][1] = fmaf(a4.z, w4.y, acc[2][1]);
      acc[2][2] = fmaf(a4.z, w4.z, acc[2][2]);
      acc[2][3] = fmaf(a4.z, w4.w, acc[2][3]);
      acc[3][0] = fmaf(a4.w, w4.x, acc[3][0]);
      acc[3][1] = fmaf(a4.w, w4.y, acc[3][1]);
      acc[3][2] = fmaf(a4.w, w4.z, acc[3][2]);
      acc[3][3] = fmaf(a4.w, w4.w, acc[3][3]);
    }
    __syncthreads();
    #pragma unroll
    for (int i = 0; i < 8; i++){ As[sc][sr + i * 8] = ra[i];
                                 Ws[sc][sr + i * 8] = rw[i]; }
    __syncthreads();
  }
  #pragma unroll 4
  for (int c = 0; c < 32; ++c){
    const float4 a4 = *(const float4*)&As[c][ty * 4];
    const float4 w4 = *(const float4*)&Ws[c][tx * 4];
    acc[0][0] = fmaf(a4.x, w4.x, acc[0][0]);
    acc[0][1] = fmaf(a4.x, w4.y, acc[0][1]);
    acc[0][2] = fmaf(a4.x, w4.z, acc[0][2]);
    acc[0][3] = fmaf(a4.x, w4.w, acc[0][3]);
    acc[1][0] = fmaf(a4.y, w4.x, acc[1][0]);
    acc[1][1] = fmaf(a4.y, w4.y, acc[1][1]);
    acc[1][2] = fmaf(a4.y, w4.z, acc[1][2]);
    acc[1][3] = fmaf(a4.y, w4.w, acc[1][3]);
    acc[2][0] = fmaf(a4.z, w4.x, acc[2][0]);
    acc[2][1] = fmaf(a4.z, w4.y, acc[2][1]);
    acc[2][2] = fmaf(a4.z, w4.z, acc[2][2]);
    acc[2][3] = fmaf(a4.z, w4.w, acc[2][3]);
    acc[3][0] = fmaf(a4.w, w4.x, acc[3][0]);
    acc[3][1] = fmaf(a4.w, w4.y, acc[3][1]);
    acc[3][2] = fmaf(a4.w, w4.z, acc[3][2]);
    acc[3][3] = fmaf(a4.w, w4.w, acc[3][3]);
  }
  float* cp = Cp + (size_t)blockIdx.z * MN;
  #pragma unroll
  for (int i = 0; i < 4; i++){
    float4 o; o.x = acc[i][0]; o.y = acc[i][1]; o.z = acc[i][2]; o.w = acc[i][3];
    *(float4*)(cp + (size_t)(mt * 64 + ty * 4 + i) * N + nt * 64 + tx * 4) = o;
  }
}

// ---------------------------------------------------------------------------
// K3: pulse (qkv row 128+b = xbar@Wqkv.T), attn_spec, soliton ODE, u=resp*v_spec
// grid 64 blocks (b*16+h), 64 threads. All outputs f32.
// ---------------------------------------------------------------------------
__global__ __launch_bounds__(64) void k3_small(
    const float* __restrict__ qkvC,
    const float* __restrict__ W1, const float* __restrict__ b1,
    const float* __restrict__ W2, const float* __restrict__ b2,
    const float* __restrict__ filt,
    const float* __restrict__ a_in, const float* __restrict__ b_in,
    float* __restrict__ u, float* __restrict__ out_pulse,
    float* __restrict__ out_resp)
{
  const int b = blockIdx.x >> 4, h = blockIdx.x & 15;
  const int d = threadIdx.x;
  __shared__ float qm[64];
  __shared__ float h1s[32];
  __shared__ float rsp[32];
  qm[d] = qkvC[(size_t)(128 + b) * 3072 + h * 64 + d] * (1.0f / 4096.0f);
  __syncthreads();
  if (d < 32){
    float z = b1[d];
    for (int j = 0; j < 64; j++) z = fmaf(qm[j], W1[d * 64 + j], z);
    h1s[d] = z / (1.0f + __expf(-z));             // silu
  }
  __syncthreads();
  if (d == 0){
    float z2 = b2[0];
    for (int j = 0; j < 32; j++) z2 = fmaf(h1s[j], W2[j], z2);
    out_pulse[b * H_ + h] = 4.0f + log1pf(__expf(z2));  // PULSE_BASE+softplus
  }
  if (d < 32){
    const int k = d;
    const float* qrow = qkvC + (size_t)(b * K_ + k) * 3072 + h * 64;
    const float* krow = qrow + 1024;
    float s = 0.f;
    for (int j = 0; j < 64; j++) s = fmaf(qrow[j], krow[j], s);
    float fg = 1.0f / (1.0f + __expf(-filt[h * 32 + k]));
    s = s * 0.125f * fg;                          // /sqrt(64)*sigmoid(filter)
    float av = a_in[0], bv = b_in[0];
    float sc = fmaxf(fabsf(s), 1e-6f);
    float sn = s / sc;
    float I  = (fabsf(s) > 0.5f) ? sn : 0.1f * sn;
    float v = 0.f, w = 0.f;
    #pragma unroll
    for (int it = 0; it < 5; ++it){
      float dv = v - v * v * v * (1.0f / 3.0f) - w + I;
      float dw = (v + av - bv * w) * 10.0f;       // /TAU
      v = fminf(fmaxf(v + 0.2f * dv, -3.0f), 3.0f);
      w = fminf(fmaxf(w + 0.2f * dw, -3.0f), 3.0f);
    }
    float r = v * sc;
    rsp[k] = r;
    out_resp[(b * H_ + h) * K_ + k] = r;
  }
  __syncthreads();
  for (int k = 0; k < 32; k++){
    u[(size_t)(b * K_ + k) * D_ + h * 64 + d] =
        rsp[k] * qkvC[(size_t)(b * K_ + k) * 3072 + 2048 + h * 64 + d];
  }
}

// ---------------------------------------------------------------------------
// k4_main: all out0 rows EXCEPT [896,1024); 32-row chunks x 256-e tiles.
// grid (4, 508), block 256 (4 waves). Wave w owns t-rows [w*8, w*8+8);
// lane owns e-quad. M is STREAMED from L2 per-k; only acc[8] live.
// ---------------------------------------------------------------------------
__global__ __launch_bounds__(256) void k4_main(
    const float* __restrict__ sb, const float* __restrict__ Mf,
    float* __restrict__ out)
{
  const int ct = blockIdx.x;
  const int yy = blockIdx.y;
  const int r0 = (yy < 28 ? yy : yy + 4) * 32;   // skip M home rows [896,1024)
  const int b  = r0 >> 12;
  const int w  = threadIdx.x >> 6;               // wave id: t-rows [w*8,w*8+8)
  const int ls = threadIdx.x & 63;               // lane: e-quad
  __shared__ __align__(16) float sbsT[32][36];   // [k][t], rows 16B-aligned
  #pragma unroll
  for (int i = 0; i < 4; i++){
    int idx = threadIdx.x + i * 256;             // 1024 = 32t * 32k
    int t = idx >> 5, k = idx & 31;
    sbsT[k][t] = sb[(size_t)(r0 + t) * K_ + k];
  }
  __syncthreads();
  float4 acc[8];
  #pragma unroll
  for (int i = 0; i < 8; i++){ acc[i].x = 0.f; acc[i].y = 0.f;
                               acc[i].z = 0.f; acc[i].w = 0.f; }
  const float4* Mg = (const float4*)(Mf + (size_t)b * K_ * D_);
  const int eq = ct * 64 + ls;                   // e-quad within D (256 f4)
  #pragma unroll 8
  for (int k = 0; k < 32; ++k){
    float4 mv = Mg[(size_t)k * 256 + eq];        // L2-hot stream
    const float4* srow = (const float4*)&sbsT[k][w * 8];  // wave-uniform
    float4 s0 = srow[0], s1 = srow[1];
    fma4(acc[0], s0.x, mv); fma4(acc[1], s0.y, mv);
    fma4(acc[2], s0.z, mv); fma4(acc[3], s0.w, mv);
    fma4(acc[4], s1.x, mv); fma4(acc[5], s1.y, mv);
    fma4(acc[6], s1.z, mv); fma4(acc[7], s1.w, mv);
  }
  float* op = out + (size_t)(r0 + w * 8) * D_ + eq * 4;
  #pragma unroll
  for (int i = 0; i < 8; i++)
    *(float4*)(op + (size_t)i * D_) = acc[i];
}

// ---------------------------------------------------------------------------
// k4_tailp: out0 rows [896,1024) — M's home — COLUMN-PARTITIONED.
// grid (64), block 256. Block j owns columns [j*16, j*16+16); race-free.
// ---------------------------------------------------------------------------
__global__ __launch_bounds__(256) void k4_tailp(
    const float* __restrict__ sb, const float* __restrict__ Mf,
    float* __restrict__ out)
{
  __shared__ float sbs[128][33];               // 16.9 KB
  __shared__ __align__(16) float Ms[32][16];   // 2 KB: this block's M columns
  const int j = blockIdx.x;
  #pragma unroll
  for (int i = 0; i < 2; i++){
    int idx = threadIdx.x + i * 256;           // 512 = 32k * 16e
    int k = idx >> 4, e = idx & 15;
    Ms[k][e] = Mf[(size_t)k * D_ + j * 16 + e];
  }
  #pragma unroll
  for (int i = 0; i < 16; i++){
    int idx = threadIdx.x + i * 256;           // 4096 = 128t * 32k
    int k = idx & 31, t = idx >> 5;
    sbs[t][k] = sb[(size_t)(896 + t) * K_ + k];
  }
  __syncthreads();
  const int t  = threadIdx.x >> 1;
  const int c0 = (threadIdx.x & 1) * 8;
  float a0 = 0.f, a1 = 0.f, a2 = 0.f, a3 = 0.f;
  float a4 = 0.f, a5 = 0.f, a6 = 0.f, a7 = 0.f;
  #pragma unroll
  for (int k = 0; k < 32; k++){
    float s = sbs[t][k];
    const float4 m0 = *(const float4*)&Ms[k][c0];
    const float4 m1 = *(const float4*)&Ms[k][c0 + 4];
    a0 = fmaf(s, m0.x, a0); a1 = fmaf(s, m0.y, a1);
    a2 = fmaf(s, m0.z, a2); a3 = fmaf(s, m0.w, a3);
    a4 = fmaf(s, m1.x, a4); a5 = fmaf(s, m1.y, a5);
    a6 = fmaf(s, m1.z, a6); a7 = fmaf(s, m1.w, a7);
  }
  float* op = out + (size_t)(896 + t) * D_ + j * 16 + c0;
  float4 o0; o0.x = a0; o0.y = a1; o0.z = a2; o0.w = a3;
  float4 o1; o1.x = a4; o1.y = a5; o1.z = a6; o1.w = a7;
  *(float4*)(op)     = o0;
  *(float4*)(op + 4) = o1;
}

// ---------------------------------------------------------------------------
extern "C" void kernel_launch(void* const* d_in, const int* in_sizes, int n_in,
                              void* d_out, int out_size, void* d_ws, size_t ws_size,
                              hipStream_t stream)
{
  const float* x    = (const float*)d_in[0];
  const float* sb   = (const float*)d_in[1];
  const float* Wqkv = (const float*)d_in[2];
  const float* Wout = (const float*)d_in[3];
  const float* a_in = (const float*)d_in[4];
  const float* b_in = (const float*)d_in[5];
  const float* W1   = (const float*)d_in[6];
  const float* b1   = (const float*)d_in[7];
  const float* W2   = (const float*)d_in[8];
  const float* b2   = (const float*)d_in[9];
  const float* filt = (const float*)d_in[10];

  float* outF = (float*)d_out;
  float* qkv  = outF + 196608;
  float* u    = outF + 786432;
  float* Mm   = outF + 917504;        // f32 M, out0 rows [896,1024)
  float* S    = outF + 1048576;       // partial slabs (sequentially reused)
  float* S2   = outF + 9699328;       // k1 reduce stage-1 (8 x 135168)
  float* S3   = outF + 5242880;       // gemm2 reduce stage-1 (4 x 131072)
  float* pulse = outF + 16777216;     // (B,H)   f32
  float* resp  = outF + 16777280;     // (B,H,K) f32

  // spectral projection partials (4 c-tiles, b=4, z=64 t-chunks); x read once
  k1_spectral_p<<<dim3(4, 4, 64), 256, 0, stream>>>(x, sb, S);
  // 2-stage reduce: 64 -> 8 -> 1 (+ zero gemm#1's pad rows)
  reduce_g<<<dim3(132, 8), 256, 0, stream>>>((const float4*)S, (float4*)S2,
                                             33792, 8, 33792);
  reduce_zp<<<dim3(192), 256, 0, stream>>>((const float4*)S2, (float4*)outF,
                                           33792, 8, 33792, 49152);

  // qkv GEMM: 16-way split-K partials (64x128 tile, 4x8 thread) -> reduce
  gemm_qkv<<<dim3(24, 3, 16), 256, 0, stream>>>(outF, Wqkv, S);
  reduce_z<<<dim3(576), 256, 0, stream>>>((const float4*)S, (float4*)qkv,
                                          147456, 16, 147456);

  k3_small<<<dim3(64), dim3(64), 0, stream>>>(qkv, W1, b1, W2, b2,
                                              filt, a_in, b_in, u,
                                              pulse, resp);

  // out GEMM: 16-way split-K partials -> 2-stage reduce: 16 -> 4 -> 1
  gemm_aw_p<<<dim3(16, 2, 16), 256, 0, stream>>>(u, Wout, S, 1024, 64, 131072);
  reduce_g<<<dim3(128, 4), 256, 0, stream>>>((const float4*)S, (float4*)S3,
                                             32768, 4, 32768);
  reduce_z<<<dim3(128), 256, 0, stream>>>((const float4*)S3, (float4*)Mm,
                                          32768, 4, 32768);

  // All rows except M's home: 32-row chunks x 4 e-tiles, M streamed from L2
  k4_main<<<dim3(4, 508), 256, 0, stream>>>(sb, Mm, outF);
  // M's home rows, column-partitioned across 64 blocks
  k4_tailp<<<dim3(64), 256, 0, stream>>>(sb, Mm, outF);
}